// Round 19
// baseline (378.251 us; speedup 1.0000x reference)
//
#include <hip/hip_runtime.h>

typedef _Float16 f16;
using f16x4 = __attribute__((ext_vector_type(4))) _Float16;
using f16x8 = __attribute__((ext_vector_type(8))) _Float16;
using f32x4 = __attribute__((ext_vector_type(4))) float;

#define HW 65536
#define NBAND 16
#define ROWS 16
#define RS 320   // k2b ring row stride in f16

// own erf (A&S 7.1.26, |err| <= 1.5e-7); __expf is HW v_exp_f32
static __device__ __forceinline__ float my_erf(float v) {
  float x = fabsf(v);
  float t = 1.f / (1.f + 0.3275911f * x);
  float y = t * (0.254829592f + t * (-0.284496736f + t * (1.421413741f
          + t * (-1.453152027f + t * 1.061405429f))));
  float r = 1.f - y * __expf(-x * x);
  return v < 0.f ? -r : r;
}
static __device__ __forceinline__ float my_gelu(float s) {
  return 0.5f * s * (1.f + my_erf(s * 0.70710678118654752f));
}

__global__ void TRA_Attention_15281493639325_kernel() {}

__global__ void k_signal(float* out, long long n, float val) {
  long long i = (long long)blockIdx.x * blockDim.x + threadIdx.x;
  long long stride = (long long)gridDim.x * blockDim.x;
  for (; i < n; i += stride) out[i] = val;
}

// ---------------------------------------------------------------------------
// K0: one-time weight convert f32 -> f16, plain [256 out][64 in] layout.
// ---------------------------------------------------------------------------
__global__ __launch_bounds__(256) void k0_wconv(
    const float* __restrict__ w_gate, const float* __restrict__ w_qkv,
    f16* __restrict__ W16)
{
  int i = blockIdx.x * 256 + threadIdx.x;     // 0..4095, 4 elems each
  int m = i >> 4, kc = i & 15;
  const float* src = (m < 64) ? (w_gate + m*64 + kc*4)
                              : (w_qkv + (m-64)*64 + kc*4);
  float4 f = *(const float4*)src;
  f16x4 pk = { (f16)f.x, (f16)f.y, (f16)f.z, (f16)f.w };
  *(f16x4*)(W16 + m*64 + kc*4) = pk;
}

// ---------------------------------------------------------------------------
// K1 (MFMA f16, T14 pipeline): fused 1x1 conv, 256 out ch.
// Persistent block = one image row (256 pos) = 4 tiles of 64 pos.
// 4-barrier tile isolation (replay-stability proven round 15 — do not relax).
// ---------------------------------------------------------------------------
__global__ __launch_bounds__(256) void k1_mfma(
    const float* __restrict__ x, const f16* __restrict__ W16,
    f16* __restrict__ A)
{
  __shared__ __align__(16) unsigned char xs[8192];    // xT 64 pos x 128B swz
  __shared__ __align__(16) f16 os[256*64];            // epilogue tile 32KB

  const int tid = threadIdx.x, blk = blockIdx.x;
  const int b = blk >> 8;
  const long long row0 = (long long)(blk & 255) * 256;

  const int wave = tid >> 6, lane = tid & 63;
  const int m0 = (wave >> 1) * 128, n0 = (wave & 1) * 32;
  const int lr = lane & 15, lg = lane >> 4;

  float4 pre[4];
  #pragma unroll
  for (int i = 0; i < 4; ++i) {
    int cid = tid + (i << 8), k = cid >> 4, c = cid & 15;
    pre[i] = *(const float4*)(x + ((long long)b*64 + k)*HW + row0 + c*4);
  }

  for (int t = 0; t < 4; ++t) {
    const long long p0 = row0 + t*64;

    #pragma unroll
    for (int i = 0; i < 4; ++i) {
      int cid = tid + (i << 8), k = cid >> 4, c = cid & 15;
      const float* e = (const float*)&pre[i];
      #pragma unroll
      for (int j = 0; j < 4; ++j) {
        int p = c*4 + j;
        int hp = ((p & 7) ^ ((p >> 3) & 7)) << 4;
        *(f16*)(xs + p*128 + ((2*k) ^ hp)) = (f16)e[j];
      }
    }
    __syncthreads();                       // barrier 1: xs ready

    if (t < 3) {                           // issue next-tile loads EARLY (T14)
      const long long pn = row0 + (t+1)*64;
      #pragma unroll
      for (int i = 0; i < 4; ++i) {
        int cid = tid + (i << 8), k = cid >> 4, c = cid & 15;
        pre[i] = *(const float4*)(x + ((long long)b*64 + k)*HW + pn + c*4);
      }
    }

    f32x4 acc[8][2];
    #pragma unroll
    for (int i = 0; i < 8; ++i)
      #pragma unroll
      for (int j = 0; j < 2; ++j) acc[i][j] = (f32x4){0.f,0.f,0.f,0.f};

    #pragma unroll
    for (int ks = 0; ks < 2; ++ks) {
      f16x8 af[8], bfr[2];
      #pragma unroll
      for (int mi = 0; mi < 8; ++mi) {
        int m = m0 + mi*16 + lr;
        af[mi] = *(const f16x8*)(W16 + m*64 + ks*32 + lg*8);  // L1-hot
      }
      #pragma unroll
      for (int ni = 0; ni < 2; ++ni) {
        int p = n0 + ni*16 + lr;
        int hp = ((p & 7) ^ ((p >> 3) & 7)) << 4;
        bfr[ni] = *(const f16x8*)(xs + p*128 + ((ks*64 + lg*16) ^ hp));
      }
      #pragma unroll
      for (int mi = 0; mi < 8; ++mi)
        #pragma unroll
        for (int ni = 0; ni < 2; ++ni)
          acc[mi][ni] = __builtin_amdgcn_mfma_f32_16x16x32_f16(
              af[mi], bfr[ni], acc[mi][ni], 0, 0, 0);
    }
    __syncthreads();                       // barrier 2: xs reads done

    #pragma unroll
    for (int mi = 0; mi < 8; ++mi)
      #pragma unroll
      for (int ni = 0; ni < 2; ++ni)
        #pragma unroll
        for (int r = 0; r < 4; ++r) {
          int m = m0 + mi*16 + lg*4 + r;
          int p = n0 + ni*16 + lr;
          os[m*64 + (p ^ ((m & 7) << 3))] = (f16)acc[mi][ni][r];
        }
    __syncthreads();                       // barrier 3: os written

    #pragma unroll
    for (int pass = 0; pass < 8; ++pass) {
      int idx = pass*256 + tid;
      int row = idx >> 3, c8 = idx & 7;
      f16x8 v = *(const f16x8*)((const unsigned char*)os + row*128
                                + ((c8 ^ (row & 7)) * 16));
      *(f16x8*)(A + ((long long)b*256 + row)*HW + p0 + c8*8) = v;
    }
    __syncthreads();                       // barrier 4: tile isolated
  }
}

// ---------------------------------------------------------------------------
// K2b (MFMA gram, ring + wide reads): dwconv for q,k of one head fused with
// the 16x16 gram via mfma_f32_16x16x32_f16 (identical A/B fragments).
// Ring staging/prefetch/barriers = round-15 (proven stable); b128 reads +
// __shfl x-halos = round-17 (proven). 1 wave per (b,h,16-row band).
// GRP: [b][h][band][80] = qq[8], kk[8], qk[64].
// ---------------------------------------------------------------------------
__device__ __forceinline__ int ridx(int c, int slot, int i) {
  return ((((c << 2) | slot) * RS) + i) ^ ((c & 7) << 3);
}

__global__ __launch_bounds__(64) void k2b_qk(
    const f16* __restrict__ A, const float* __restrict__ w_qkv_dw,
    float* __restrict__ GRP)
{
  __shared__ __align__(16) f16 ring[16*4*RS];
  const int lane = threadIdx.x, blk = blockIdx.x;
  const int band = blk & (NBAND-1), h = (blk >> 4) & 7, b = blk >> 7;

  const int c  = lane & 15, g  = lane >> 4;   // compute role
  const int cs = lane >> 2, q4 = lane & 3;    // staging role

  const int wrow = (c < 8) ? (h*8 + c) : (64 + h*8 + (c - 8));
  float wq[9];
  #pragma unroll
  for (int j = 0; j < 9; ++j) wq[j] = w_qkv_dw[wrow*9 + j];

  const f16* sbase = A + ((long long)b*256 +
      (cs < 8 ? 64 + h*8 + cs : 128 + h*8 + (cs - 8))) * HW;

  auto load_row = [&](int yy, uint4* r) {
    if (yy >= 0 && yy < 256) {
      const f16* p = sbase + yy*256 + q4*64;
      #pragma unroll
      for (int t = 0; t < 8; ++t) r[t] = *(const uint4*)(p + t*8);
    } else {
      #pragma unroll
      for (int t = 0; t < 8; ++t) r[t] = make_uint4(0u,0u,0u,0u);
    }
  };
  auto write_row = [&](int slot, const uint4* r) {
    #pragma unroll
    for (int t = 0; t < 8; ++t)
      *(uint4*)&ring[ridx(cs, slot, 8 + q4*64 + t*8)] = r[t];
  };

  auto conv_accum = [&](const f16x8* R, const float* w, float* fr, int q) {
    float v[10];
    #pragma unroll
    for (int t = 0; t < 8; ++t) v[1 + t] = (float)R[q][t];
    float e7p = (q > 0) ? (float)R[q-1][7] : 0.f;
    float e0n = (q < 7) ? (float)R[q+1][0] : 0.f;
    float L1 = __shfl(v[8], lane - 16);          // (c,g-1) chunk q, e7
    float L2 = __shfl(e7p, (lane & 15) + 48);    // (c,3) chunk q-1, e7
    float Q1 = __shfl(v[1], lane + 16);          // (c,g+1) chunk q, e0
    float Q2 = __shfl(e0n, lane & 15);           // (c,0) chunk q+1, e0
    v[0] = (g > 0) ? L1 : ((q > 0) ? L2 : 0.f);
    v[9] = (g < 3) ? Q1 : ((q < 7) ? Q2 : 0.f);
    #pragma unroll
    for (int j = 0; j < 8; ++j)
      fr[j] += w[0]*v[j] + w[1]*v[j+1] + w[2]*v[j+2];
  };

  f32x4 acc = (f32x4){0.f, 0.f, 0.f, 0.f};

  const int y0 = band * ROWS;
  {
    uint4 r[8];
    load_row(y0-1, r); write_row((y0+3)&3, r);
    load_row(y0,   r); write_row((y0+4)&3, r);
    load_row(y0+1, r); write_row((y0+5)&3, r);
  }
  __syncthreads();

  for (int y = y0; y < y0 + ROWS; ++y) {
    uint4 r[8];
    const bool pf = (y + 2 <= y0 + ROWS);
    if (pf) load_row(y + 2, r);              // issue early (T14)

    const int s0 = (y+3)&3, s1 = (y+4)&3, s2 = (y+5)&3;
    f16x8 Rm[8], Rc[8], Rp[8];
    #pragma unroll
    for (int q = 0; q < 8; ++q) {
      Rm[q] = *(const f16x8*)&ring[ridx(c, s0, 8 + q*32 + g*8)];
      Rc[q] = *(const f16x8*)&ring[ridx(c, s1, 8 + q*32 + g*8)];
      Rp[q] = *(const f16x8*)&ring[ridx(c, s2, 8 + q*32 + g*8)];
    }

    #pragma unroll
    for (int q = 0; q < 8; ++q) {
      float fr[8] = {0.f,0.f,0.f,0.f,0.f,0.f,0.f,0.f};
      conv_accum(Rm, wq + 0, fr, q);
      conv_accum(Rc, wq + 3, fr, q);
      conv_accum(Rp, wq + 6, fr, q);
      f16x8 frag;
      #pragma unroll
      for (int j = 0; j < 8; ++j) frag[j] = (f16)fr[j];
      acc = __builtin_amdgcn_mfma_f32_16x16x32_f16(frag, frag, acc, 0, 0, 0);
    }

    if (pf) write_row((y+6)&3, r);           // write late, after reads
    __syncthreads();
  }

  const long long gbase = (long long)((b*8 + h)*NBAND + band) * 80;
  #pragma unroll
  for (int reg = 0; reg < 4; ++reg) {
    int rrow = g*4 + reg;
    float val = acc[reg];
    if (rrow == c) GRP[gbase + c] = val;
    else if (rrow < 8 && c >= 8) GRP[gbase + 16 + rrow*8 + (c-8)] = val;
  }
}

// ---------------------------------------------------------------------------
// K2c: reduce band partials, normalize, temperature, softmax. grid = nb*8
// ---------------------------------------------------------------------------
__global__ __launch_bounds__(64) void k2c_attn(
    const float* __restrict__ GRP, const float* __restrict__ temp,
    float* __restrict__ ATT)
{
  __shared__ float s[80];
  const int tid = threadIdx.x;
  const int h = blockIdx.x & 7, b = blockIdx.x >> 3;
  for (int i = tid; i < 80; i += 64) {
    float v = 0.f;
    for (int band = 0; band < NBAND; ++band)
      v += GRP[(((b*8 + h)*NBAND + band) * 80) + i];
    s[i] = v;
  }
  __syncthreads();
  const int c = tid >> 3, d = tid & 7;
  float nq = fmaxf(sqrtf(s[c]), 1e-12f);
  float nk = fmaxf(sqrtf(s[8 + d]), 1e-12f);
  float logit = s[16 + c*8 + d] / (nq * nk) * temp[h];
  float m = logit;
  #pragma unroll
  for (int off = 4; off; off >>= 1) m = fmaxf(m, __shfl_xor(m, off));
  float e = __expf(logit - m);
  float sum = e;
  #pragma unroll
  for (int off = 4; off; off >>= 1) sum += __shfl_xor(sum, off);
  ATT[((b*8 + h)*8 + c)*8 + d] = e / sum;
}

// ---------------------------------------------------------------------------
// K3 (FUSED dwconv+gelu+gating+MFMA proj): computes Vv/GG inline from A
// (k2a's verified conv math: uint4 row loads, __shfl x-halos, f32 taps),
// av accumulation with attn from LDS, gelu-gating overwriting av in place,
// then the unchanged MFMA projection. Eliminates k2a and the Vv/GG buffers.
// Block = (b, y image row), 256 thr = (pg = tid&31, hd = tid>>5).
// grid = nb*256.
// ---------------------------------------------------------------------------
__global__ __launch_bounds__(256) void k3_fused(
    const f16* __restrict__ A, const float* __restrict__ ATT,
    const float* __restrict__ w_gate_dw, const float* __restrict__ w_qkv_dw,
    const float* __restrict__ w_proj, float* __restrict__ out)
{
  __shared__ __align__(16) unsigned char lds[64*128 + 256*128 + 2048];
  unsigned char* wl = lds;                    // wp f16 [64co][64ch] swz rows
  unsigned char* xs = lds + 64*128;           // g  f16 [256pos][64ch] swz rows
  float* attn_s = (float*)(lds + 64*128 + 256*128);

  const int tid = threadIdx.x;
  const int y = blockIdx.x & 255, b = blockIdx.x >> 8;
  const int pg = tid & 31, hd = tid >> 5;
  const int lane = tid & 63;

  // stage wp (f32 -> f16, swizzled) + attn
  for (int cid = tid; cid < 1024; cid += 256) {
    int m = cid >> 4, kc = cid & 15;
    float4 f = *(const float4*)(w_proj + m*64 + kc*4);
    int hm = ((m & 7) ^ ((m >> 3) & 7)) << 4;
    f16x4 pk = { (f16)f.x, (f16)f.y, (f16)f.z, (f16)f.w };
    *(f16x4*)(wl + m*128 + ((kc*8) ^ hm)) = pk;
  }
  for (int i = tid; i < 512; i += 256) attn_s[i] = ATT[b*512 + i];
  __syncthreads();

  // per-channel 3x3 dwconv at row y, positions pg*8..pg*8+7 (k2a math)
  auto conv_ch = [&](const f16* chbase, const float* w, float* out8) {
    uint4 q[3];
    #pragma unroll
    for (int rI = 0; rI < 3; ++rI) {
      int yy = y - 1 + rI;
      if (yy >= 0 && yy < 256)
        q[rI] = *(const uint4*)(chbase + yy*256 + pg*8);
      else
        q[rI] = make_uint4(0u, 0u, 0u, 0u);
    }
    float rr[3][10];
    #pragma unroll
    for (int rI = 0; rI < 3; ++rI) {
      const f16* e = (const f16*)&q[rI];
      float* r = rr[rI];
      #pragma unroll
      for (int t = 0; t < 8; ++t) r[1 + t] = (float)e[t];
      float lf = __shfl(r[8], lane - 1);
      float rf = __shfl(r[1], lane + 1);
      r[0] = (pg == 0)  ? 0.f : lf;
      r[9] = (pg == 31) ? 0.f : rf;
    }
    #pragma unroll
    for (int j = 0; j < 8; ++j)
      out8[j] = w[0]*rr[0][j] + w[1]*rr[0][j+1] + w[2]*rr[0][j+2]
              + w[3]*rr[1][j] + w[4]*rr[1][j+1] + w[5]*rr[1][j+2]
              + w[6]*rr[2][j] + w[7]*rr[2][j+1] + w[8]*rr[2][j+2];
  };

  float av[8][8];
  #pragma unroll
  for (int c = 0; c < 8; ++c)
    #pragma unroll
    for (int j = 0; j < 8; ++j) av[c][j] = 0.f;

  // v channels: conv -> accumulate attn@v
  #pragma unroll 2
  for (int d = 0; d < 8; ++d) {
    const f16* chb = A + ((long long)b*256 + 192 + hd*8 + d) * HW;
    float wv[9];
    #pragma unroll
    for (int j = 0; j < 9; ++j) wv[j] = w_qkv_dw[(128 + hd*8 + d)*9 + j];
    float vc[8];
    conv_ch(chb, wv, vc);
    float ac[8];
    #pragma unroll
    for (int c = 0; c < 8; ++c) ac[c] = attn_s[hd*64 + c*8 + d];
    #pragma unroll
    for (int c = 0; c < 8; ++c)
      #pragma unroll
      for (int j = 0; j < 8; ++j) av[c][j] += ac[c] * vc[j];
  }

  // gate channels: conv -> gelu -> gate av in place
  #pragma unroll 2
  for (int c = 0; c < 8; ++c) {
    const f16* chb = A + ((long long)b*256 + hd*8 + c) * HW;
    float wg9[9];
    #pragma unroll
    for (int j = 0; j < 9; ++j) wg9[j] = w_gate_dw[(hd*8 + c)*9 + j];
    float gc[8];
    conv_ch(chb, wg9, gc);
    #pragma unroll
    for (int j = 0; j < 8; ++j) av[c][j] = my_gelu(gc[j]) * av[c][j];
  }

  // write g tile to xs (same layout as before)
  #pragma unroll
  for (int j = 0; j < 8; ++j) {
    int p = pg*8 + j;
    int hp = ((p & 7) ^ ((p >> 3) & 7)) << 4;
    f16x8 st;
    #pragma unroll
    for (int c = 0; c < 8; ++c) st[c] = (f16)av[c][j];
    *(f16x8*)(xs + p*128 + ((hd*16) ^ hp)) = st;
  }
  __syncthreads();

  // MFMA proj: wave w handles pos strip n0=w*64; M=64, N=64, K=64.
  const int wave = tid >> 6;
  const int n0 = wave * 64;
  const int lr = lane & 15, lg = lane >> 4;

  f32x4 acc[4][4];
  #pragma unroll
  for (int i = 0; i < 4; ++i)
    #pragma unroll
    for (int j = 0; j < 4; ++j) acc[i][j] = (f32x4){0.f,0.f,0.f,0.f};

  #pragma unroll
  for (int ks = 0; ks < 2; ++ks) {
    f16x8 af[4], bfr[4];
    #pragma unroll
    for (int mi = 0; mi < 4; ++mi) {
      int m = mi*16 + lr;
      int hm = ((m & 7) ^ ((m >> 3) & 7)) << 4;
      af[mi] = *(const f16x8*)(wl + m*128 + ((ks*64 + lg*16) ^ hm));
    }
    #pragma unroll
    for (int ni = 0; ni < 4; ++ni) {
      int p = n0 + ni*16 + lr;
      int hp = ((p & 7) ^ ((p >> 3) & 7)) << 4;
      bfr[ni] = *(const f16x8*)(xs + p*128 + ((ks*64 + lg*16) ^ hp));
    }
    #pragma unroll
    for (int mi = 0; mi < 4; ++mi)
      #pragma unroll
      for (int ni = 0; ni < 4; ++ni)
        acc[mi][ni] = __builtin_amdgcn_mfma_f32_16x16x32_f16(
            af[mi], bfr[ni], acc[mi][ni], 0, 0, 0);
  }

  const long long obase = (long long)b*64*HW + (long long)y*256;
  #pragma unroll
  for (int mi = 0; mi < 4; ++mi)
    #pragma unroll
    for (int ni = 0; ni < 4; ++ni)
      #pragma unroll
      for (int r = 0; r < 4; ++r) {
        int m = mi*16 + lg*4 + r;
        int p = n0 + ni*16 + lr;
        out[obase + (long long)m*HW + p] = acc[mi][ni][r];
      }
}

// ---------------------------------------------------------------------------
extern "C" void kernel_launch(void* const* d_in, const int* in_sizes, int n_in,
                              void* d_out, int out_size, void* d_ws, size_t ws_size,
                              hipStream_t stream)
{
  float* out = (float*)d_out;

  int mp[7] = {-1,-1,-1,-1,-1,-1,-1};
  bool ok = (n_in == 7);
  if (ok) {
    int n4 = 0;
    for (int i = 0; i < 7; ++i) {
      long s = in_sizes[i];
      if      (s == 33554432) mp[0] = i;            // x
      else if (s == 576)      mp[2] = i;            // w_gate_dw
      else if (s == 12288)    mp[3] = i;            // w_qkv
      else if (s == 1728)     mp[4] = i;            // w_qkv_dw
      else if (s == 8)        mp[6] = i;            // temperature
      else if (s == 4096)     { if (n4 == 0) mp[1] = i; else mp[5] = i; ++n4; }
    }
    ok = ok && (n4 == 2);
    for (int i = 0; i < 7; ++i) ok = ok && (mp[i] >= 0);
  }
  if (!ok) { k_signal<<<2048,256,0,stream>>>(out, (long long)out_size, 2000.0f); return; }
  if (out_size != 33554432) { k_signal<<<2048,256,0,stream>>>(out, (long long)out_size, 3000.0f); return; }

  const float* x    = (const float*)d_in[mp[0]];
  const float* wg   = (const float*)d_in[mp[1]];
  const float* wgd  = (const float*)d_in[mp[2]];
  const float* wqkv = (const float*)d_in[mp[3]];
  const float* wqd  = (const float*)d_in[mp[4]];
  const float* wpj  = (const float*)d_in[mp[5]];
  const float* tp   = (const float*)d_in[mp[6]];

  unsigned char* ws = (unsigned char*)d_ws;
  const size_t GRP_SZ   = 8UL*8*NBAND*80*4;            // 327,680
  const size_t FULL     = 402653184UL + GRP_SZ + 16384UL + 32768UL;
  const size_t PERB_GRP = 8UL*NBAND*80*4;              // 40,960
  const size_t PERB     = 50331648UL + PERB_GRP + 2048UL + 32768UL;

  if (ws != nullptr && ws_size >= FULL) {
    f16*   A    = (f16*)ws;                         // 268,435,456 (Vv/GG slots unused now)
    float* GRP  = (float*)(ws + 402653184UL);
    float* ATT  = (float*)(ws + 402653184UL + GRP_SZ);
    f16*   W16  = (f16*)(ws + 402653184UL + GRP_SZ + 16384UL);
    k0_wconv<<<16,   256, 0, stream>>>(wg, wqkv, W16);
    k1_mfma <<<2048, 256, 0, stream>>>(x, W16, A);
    k2b_qk  <<<8*8*NBAND, 64, 0, stream>>>(A, wqd, GRP);
    k2c_attn<<<64,   64,  0, stream>>>(GRP, tp, ATT);
    k3_fused<<<2048, 256, 0, stream>>>(A, ATT, wgd, wqd, wpj, out);
  } else if (ws != nullptr && ws_size >= PERB) {
    f16*   A    = (f16*)ws;
    float* GRP  = (float*)(ws + 50331648UL);
    float* ATT  = (float*)(ws + 50331648UL + PERB_GRP);
    f16*   W16  = (f16*)(ws + 50331648UL + PERB_GRP + 2048UL);
    k0_wconv<<<16, 256, 0, stream>>>(wg, wqkv, W16);
    for (int b = 0; b < 8; ++b) {
      const float* xb = x + (long long)b*64*HW;
      float* ob = out + (long long)b*64*HW;
      k1_mfma <<<256,  256, 0, stream>>>(xb, W16, A);
      k2b_qk  <<<8*NBAND, 64, 0, stream>>>(A, wqd, GRP);
      k2c_attn<<<8,    64,  0, stream>>>(GRP, tp, ATT);
      k3_fused<<<256,  256, 0, stream>>>(A, ATT, wgd, wqd, wpj, ob);
    }
  } else {
    k_signal<<<2048,256,0,stream>>>(out, (long long)out_size, 1000.0f);
  }
}

// Round 20
// 288.028 us; speedup vs baseline: 1.3132x; 1.3132x over previous
//
#include <hip/hip_runtime.h>

typedef _Float16 f16;
using f16x4 = __attribute__((ext_vector_type(4))) _Float16;
using f16x8 = __attribute__((ext_vector_type(8))) _Float16;
using f32x4 = __attribute__((ext_vector_type(4))) float;

#define HW 65536
#define NBAND 32
#define ROWS 8
#define RS 320   // k2b ring row stride in f16

// own erf (A&S 7.1.26, |err| <= 1.5e-7); __expf is HW v_exp_f32
static __device__ __forceinline__ float my_erf(float v) {
  float x = fabsf(v);
  float t = 1.f / (1.f + 0.3275911f * x);
  float y = t * (0.254829592f + t * (-0.284496736f + t * (1.421413741f
          + t * (-1.453152027f + t * 1.061405429f))));
  float r = 1.f - y * __expf(-x * x);
  return v < 0.f ? -r : r;
}
static __device__ __forceinline__ float my_gelu(float s) {
  return 0.5f * s * (1.f + my_erf(s * 0.70710678118654752f));
}

__global__ void TRA_Attention_15281493639325_kernel() {}

__global__ void k_signal(float* out, long long n, float val) {
  long long i = (long long)blockIdx.x * blockDim.x + threadIdx.x;
  long long stride = (long long)gridDim.x * blockDim.x;
  for (; i < n; i += stride) out[i] = val;
}

// ---------------------------------------------------------------------------
// K0: one-time weight convert f32 -> f16, plain [256 out][64 in] layout.
// ---------------------------------------------------------------------------
__global__ __launch_bounds__(256) void k0_wconv(
    const float* __restrict__ w_gate, const float* __restrict__ w_qkv,
    f16* __restrict__ W16)
{
  int i = blockIdx.x * 256 + threadIdx.x;     // 0..4095, 4 elems each
  int m = i >> 4, kc = i & 15;
  const float* src = (m < 64) ? (w_gate + m*64 + kc*4)
                              : (w_qkv + (m-64)*64 + kc*4);
  float4 f = *(const float4*)src;
  f16x4 pk = { (f16)f.x, (f16)f.y, (f16)f.z, (f16)f.w };
  *(f16x4*)(W16 + m*64 + kc*4) = pk;
}

// ---------------------------------------------------------------------------
// K1 (MFMA f16, T14 pipeline): fused 1x1 conv, 256 out ch.
// Persistent block = one image row (256 pos) = 4 tiles of 64 pos.
// 4-barrier tile isolation (replay-stability proven round 15 — do not relax).
// ---------------------------------------------------------------------------
__global__ __launch_bounds__(256) void k1_mfma(
    const float* __restrict__ x, const f16* __restrict__ W16,
    f16* __restrict__ A)
{
  __shared__ __align__(16) unsigned char xs[8192];    // xT 64 pos x 128B swz
  __shared__ __align__(16) f16 os[256*64];            // epilogue tile 32KB

  const int tid = threadIdx.x, blk = blockIdx.x;
  const int b = blk >> 8;
  const long long row0 = (long long)(blk & 255) * 256;

  const int wave = tid >> 6, lane = tid & 63;
  const int m0 = (wave >> 1) * 128, n0 = (wave & 1) * 32;
  const int lr = lane & 15, lg = lane >> 4;

  float4 pre[4];
  #pragma unroll
  for (int i = 0; i < 4; ++i) {
    int cid = tid + (i << 8), k = cid >> 4, c = cid & 15;
    pre[i] = *(const float4*)(x + ((long long)b*64 + k)*HW + row0 + c*4);
  }

  for (int t = 0; t < 4; ++t) {
    const long long p0 = row0 + t*64;

    #pragma unroll
    for (int i = 0; i < 4; ++i) {
      int cid = tid + (i << 8), k = cid >> 4, c = cid & 15;
      const float* e = (const float*)&pre[i];
      #pragma unroll
      for (int j = 0; j < 4; ++j) {
        int p = c*4 + j;
        int hp = ((p & 7) ^ ((p >> 3) & 7)) << 4;
        *(f16*)(xs + p*128 + ((2*k) ^ hp)) = (f16)e[j];
      }
    }
    __syncthreads();                       // barrier 1: xs ready

    if (t < 3) {                           // issue next-tile loads EARLY (T14)
      const long long pn = row0 + (t+1)*64;
      #pragma unroll
      for (int i = 0; i < 4; ++i) {
        int cid = tid + (i << 8), k = cid >> 4, c = cid & 15;
        pre[i] = *(const float4*)(x + ((long long)b*64 + k)*HW + pn + c*4);
      }
    }

    f32x4 acc[8][2];
    #pragma unroll
    for (int i = 0; i < 8; ++i)
      #pragma unroll
      for (int j = 0; j < 2; ++j) acc[i][j] = (f32x4){0.f,0.f,0.f,0.f};

    #pragma unroll
    for (int ks = 0; ks < 2; ++ks) {
      f16x8 af[8], bfr[2];
      #pragma unroll
      for (int mi = 0; mi < 8; ++mi) {
        int m = m0 + mi*16 + lr;
        af[mi] = *(const f16x8*)(W16 + m*64 + ks*32 + lg*8);  // L1-hot
      }
      #pragma unroll
      for (int ni = 0; ni < 2; ++ni) {
        int p = n0 + ni*16 + lr;
        int hp = ((p & 7) ^ ((p >> 3) & 7)) << 4;
        bfr[ni] = *(const f16x8*)(xs + p*128 + ((ks*64 + lg*16) ^ hp));
      }
      #pragma unroll
      for (int mi = 0; mi < 8; ++mi)
        #pragma unroll
        for (int ni = 0; ni < 2; ++ni)
          acc[mi][ni] = __builtin_amdgcn_mfma_f32_16x16x32_f16(
              af[mi], bfr[ni], acc[mi][ni], 0, 0, 0);
    }
    __syncthreads();                       // barrier 2: xs reads done

    #pragma unroll
    for (int mi = 0; mi < 8; ++mi)
      #pragma unroll
      for (int ni = 0; ni < 2; ++ni)
        #pragma unroll
        for (int r = 0; r < 4; ++r) {
          int m = m0 + mi*16 + lg*4 + r;
          int p = n0 + ni*16 + lr;
          os[m*64 + (p ^ ((m & 7) << 3))] = (f16)acc[mi][ni][r];
        }
    __syncthreads();                       // barrier 3: os written

    #pragma unroll
    for (int pass = 0; pass < 8; ++pass) {
      int idx = pass*256 + tid;
      int row = idx >> 3, c8 = idx & 7;
      f16x8 v = *(const f16x8*)((const unsigned char*)os + row*128
                                + ((c8 ^ (row & 7)) * 16));
      *(f16x8*)(A + ((long long)b*256 + row)*HW + p0 + c8*8) = v;
    }
    __syncthreads();                       // barrier 4: tile isolated
  }
}

// ---------------------------------------------------------------------------
// K2a (reg-rolling, LDS-free): depthwise 3x3 for gate (+GELU) and v channels.
// Block index interleaves gate/v (isv = blk&1) so every CU gets a mix of
// heavy (gelu) and light blocks — fixes the homogeneous-batch dispatch tail.
// grid = nb*512: blk = b*512 + c*8 + yband*2 + isv.
// ---------------------------------------------------------------------------
__global__ __launch_bounds__(256) void k2a_dw(
    const f16* __restrict__ A, const float* __restrict__ w_gate_dw,
    const float* __restrict__ w_qkv_dw, f16* __restrict__ Vv, f16* __restrict__ GG)
{
  const int tid = threadIdx.x, blk = blockIdx.x;
  const bool isv = blk & 1;
  const int yband = (blk >> 1) & 3;
  const int c = (blk >> 3) & 63;
  const int b = blk >> 9;
  const f16* src = A + ((long long)b*256 + (isv ? 192 + c : c)) * HW;
  const float* wsrc = isv ? (w_qkv_dw + (128 + c)*9) : (w_gate_dw + c*9);
  f16* dst = (isv ? Vv : GG) + ((long long)b*64 + c) * HW;

  float wd[9];
  #pragma unroll
  for (int j = 0; j < 9; ++j) wd[j] = wsrc[j];

  const int xc = tid & 31, ysub = tid >> 5;
  const int lane = tid & 63;
  const int xbase = xc * 8;
  const int y0 = yband * 64 + ysub * 8;

  float rb[3][10];

  auto load_row = [&](int y, float* r) {
    if (y >= 0 && y < 256) {
      uint4 raw = *(const uint4*)(src + y*256 + xbase);
      const f16* e = (const f16*)&raw;
      #pragma unroll
      for (int t = 0; t < 8; ++t) r[1 + t] = (float)e[t];
    } else {
      #pragma unroll
      for (int t = 0; t < 8; ++t) r[1 + t] = 0.f;
    }
    float lf = __shfl(r[8], lane - 1);
    float rf = __shfl(r[1], lane + 1);
    r[0] = (xc == 0)  ? 0.f : lf;
    r[9] = (xc == 31) ? 0.f : rf;
  };

  load_row(y0 - 1, rb[0]);
  load_row(y0,     rb[1]);

  #pragma unroll
  for (int i = 0; i < 8; ++i) {
    load_row(y0 + i + 1, rb[(i + 2) % 3]);
    const float* rm = rb[i % 3];
    const float* r0 = rb[(i + 1) % 3];
    const float* rp = rb[(i + 2) % 3];
    f16x8 st;
    #pragma unroll
    for (int j = 0; j < 8; ++j) {
      float s = wd[0]*rm[j] + wd[1]*rm[j+1] + wd[2]*rm[j+2]
              + wd[3]*r0[j] + wd[4]*r0[j+1] + wd[5]*r0[j+2]
              + wd[6]*rp[j] + wd[7]*rp[j+1] + wd[8]*rp[j+2];
      if (!isv) s = my_gelu(s);
      st[j] = (f16)s;
    }
    *(f16x8*)(dst + (y0 + i)*256 + xbase) = st;
  }
}

// ---------------------------------------------------------------------------
// K2b (MFMA gram, ring + wide reads): dwconv for q,k of one head fused with
// the 16x16 gram via mfma_f32_16x16x32_f16 (identical A/B fragments).
// Ring staging/prefetch/barriers = round-15 (proven stable); b128 reads +
// __shfl x-halos = round-17 (proven). 1 wave per (b,h,ROWS-row band).
// NBAND=32 (8-row bands) for 2x grid occupancy.
// GRP: [b][h][band][80] = qq[8], kk[8], qk[64].
// ---------------------------------------------------------------------------
__device__ __forceinline__ int ridx(int c, int slot, int i) {
  return ((((c << 2) | slot) * RS) + i) ^ ((c & 7) << 3);
}

__global__ __launch_bounds__(64) void k2b_qk(
    const f16* __restrict__ A, const float* __restrict__ w_qkv_dw,
    float* __restrict__ GRP)
{
  __shared__ __align__(16) f16 ring[16*4*RS];
  const int lane = threadIdx.x, blk = blockIdx.x;
  const int band = blk & (NBAND-1), h = (blk / NBAND) & 7, b = blk / (NBAND*8);

  const int c  = lane & 15, g  = lane >> 4;   // compute role
  const int cs = lane >> 2, q4 = lane & 3;    // staging role

  const int wrow = (c < 8) ? (h*8 + c) : (64 + h*8 + (c - 8));
  float wq[9];
  #pragma unroll
  for (int j = 0; j < 9; ++j) wq[j] = w_qkv_dw[wrow*9 + j];

  const f16* sbase = A + ((long long)b*256 +
      (cs < 8 ? 64 + h*8 + cs : 128 + h*8 + (cs - 8))) * HW;

  auto load_row = [&](int yy, uint4* r) {
    if (yy >= 0 && yy < 256) {
      const f16* p = sbase + yy*256 + q4*64;
      #pragma unroll
      for (int t = 0; t < 8; ++t) r[t] = *(const uint4*)(p + t*8);
    } else {
      #pragma unroll
      for (int t = 0; t < 8; ++t) r[t] = make_uint4(0u,0u,0u,0u);
    }
  };
  auto write_row = [&](int slot, const uint4* r) {
    #pragma unroll
    for (int t = 0; t < 8; ++t)
      *(uint4*)&ring[ridx(cs, slot, 8 + q4*64 + t*8)] = r[t];
  };

  auto conv_accum = [&](const f16x8* R, const float* w, float* fr, int q) {
    float v[10];
    #pragma unroll
    for (int t = 0; t < 8; ++t) v[1 + t] = (float)R[q][t];
    float e7p = (q > 0) ? (float)R[q-1][7] : 0.f;
    float e0n = (q < 7) ? (float)R[q+1][0] : 0.f;
    float L1 = __shfl(v[8], lane - 16);          // (c,g-1) chunk q, e7
    float L2 = __shfl(e7p, (lane & 15) + 48);    // (c,3) chunk q-1, e7
    float Q1 = __shfl(v[1], lane + 16);          // (c,g+1) chunk q, e0
    float Q2 = __shfl(e0n, lane & 15);           // (c,0) chunk q+1, e0
    v[0] = (g > 0) ? L1 : ((q > 0) ? L2 : 0.f);
    v[9] = (g < 3) ? Q1 : ((q < 7) ? Q2 : 0.f);
    #pragma unroll
    for (int j = 0; j < 8; ++j)
      fr[j] += w[0]*v[j] + w[1]*v[j+1] + w[2]*v[j+2];
  };

  f32x4 acc = (f32x4){0.f, 0.f, 0.f, 0.f};

  const int y0 = band * ROWS;
  {
    uint4 r[8];
    load_row(y0-1, r); write_row((y0+3)&3, r);
    load_row(y0,   r); write_row((y0+4)&3, r);
    load_row(y0+1, r); write_row((y0+5)&3, r);
  }
  __syncthreads();

  for (int y = y0; y < y0 + ROWS; ++y) {
    uint4 r[8];
    const bool pf = (y + 2 <= y0 + ROWS);
    if (pf) load_row(y + 2, r);              // issue early (T14)

    const int s0 = (y+3)&3, s1 = (y+4)&3, s2 = (y+5)&3;
    f16x8 Rm[8], Rc[8], Rp[8];
    #pragma unroll
    for (int q = 0; q < 8; ++q) {
      Rm[q] = *(const f16x8*)&ring[ridx(c, s0, 8 + q*32 + g*8)];
      Rc[q] = *(const f16x8*)&ring[ridx(c, s1, 8 + q*32 + g*8)];
      Rp[q] = *(const f16x8*)&ring[ridx(c, s2, 8 + q*32 + g*8)];
    }

    #pragma unroll
    for (int q = 0; q < 8; ++q) {
      float fr[8] = {0.f,0.f,0.f,0.f,0.f,0.f,0.f,0.f};
      conv_accum(Rm, wq + 0, fr, q);
      conv_accum(Rc, wq + 3, fr, q);
      conv_accum(Rp, wq + 6, fr, q);
      f16x8 frag;
      #pragma unroll
      for (int j = 0; j < 8; ++j) frag[j] = (f16)fr[j];
      acc = __builtin_amdgcn_mfma_f32_16x16x32_f16(frag, frag, acc, 0, 0, 0);
    }

    if (pf) write_row((y+6)&3, r);           // write late, after reads
    __syncthreads();
  }

  const long long gbase = (long long)((b*8 + h)*NBAND + band) * 80;
  #pragma unroll
  for (int reg = 0; reg < 4; ++reg) {
    int rrow = g*4 + reg;
    float val = acc[reg];
    if (rrow == c) GRP[gbase + c] = val;
    else if (rrow < 8 && c >= 8) GRP[gbase + 16 + rrow*8 + (c-8)] = val;
  }
}

// ---------------------------------------------------------------------------
// K2c: reduce band partials, normalize, temperature, softmax. grid = nb*8
// ---------------------------------------------------------------------------
__global__ __launch_bounds__(64) void k2c_attn(
    const float* __restrict__ GRP, const float* __restrict__ temp,
    float* __restrict__ ATT)
{
  __shared__ float s[80];
  const int tid = threadIdx.x;
  const int h = blockIdx.x & 7, b = blockIdx.x >> 3;
  for (int i = tid; i < 80; i += 64) {
    float v = 0.f;
    for (int band = 0; band < NBAND; ++band)
      v += GRP[(((b*8 + h)*NBAND + band) * 80) + i];
    s[i] = v;
  }
  __syncthreads();
  const int c = tid >> 3, d = tid & 7;
  float nq = fmaxf(sqrtf(s[c]), 1e-12f);
  float nk = fmaxf(sqrtf(s[8 + d]), 1e-12f);
  float logit = s[16 + c*8 + d] / (nq * nk) * temp[h];
  float m = logit;
  #pragma unroll
  for (int off = 4; off; off >>= 1) m = fmaxf(m, __shfl_xor(m, off));
  float e = __expf(logit - m);
  float sum = e;
  #pragma unroll
  for (int off = 4; off; off >>= 1) sum += __shfl_xor(sum, off);
  ATT[((b*8 + h)*8 + c)*8 + d] = e / sum;
}

// ---------------------------------------------------------------------------
// K3 (MFMA proj): g = gelu(gate)*(attn@v) -> f16 LDS tile -> MFMA with
// w_proj (f16) -> f32 out. Block = 256 thr, one image row (256 pos).
// grid = nb*256.
// ---------------------------------------------------------------------------
__global__ __launch_bounds__(256) void k3_out(
    const f16* __restrict__ Vv, const f16* __restrict__ GG,
    const float* __restrict__ ATT, const float* __restrict__ w_proj,
    float* __restrict__ out)
{
  __shared__ __align__(16) unsigned char lds[64*128 + 256*128 + 2048];
  unsigned char* wl = lds;                    // wp f16 [64co][64ch] swz rows
  unsigned char* xs = lds + 64*128;           // g  f16 [256pos][64ch] swz rows
  float* attn_s = (float*)(lds + 64*128 + 256*128);

  const int tid = threadIdx.x;
  const int y = blockIdx.x & 255, b = blockIdx.x >> 8;

  for (int cid = tid; cid < 1024; cid += 256) {
    int m = cid >> 4, kc = cid & 15;
    float4 f = *(const float4*)(w_proj + m*64 + kc*4);
    int hm = ((m & 7) ^ ((m >> 3) & 7)) << 4;
    f16x4 pk = { (f16)f.x, (f16)f.y, (f16)f.z, (f16)f.w };
    *(f16x4*)(wl + m*128 + ((kc*8) ^ hm)) = pk;
  }
  for (int i = tid; i < 512; i += 256) attn_s[i] = ATT[b*512 + i];
  __syncthreads();

  {
    const int pg = tid & 31, hd = tid >> 5;
    const long long base = ((long long)b*64 + hd*8)*HW + (long long)y*256 + pg*8;
    f16x8 vv[8], gg[8];
    #pragma unroll
    for (int d = 0; d < 8; ++d)
      vv[d] = *(const f16x8*)(Vv + base + (long long)d*HW);
    #pragma unroll
    for (int c = 0; c < 8; ++c)
      gg[c] = *(const f16x8*)(GG + base + (long long)c*HW);
    float a[8][8];
    #pragma unroll
    for (int c = 0; c < 8; ++c)
      #pragma unroll
      for (int d = 0; d < 8; ++d) a[c][d] = attn_s[hd*64 + c*8 + d];
    #pragma unroll
    for (int j = 0; j < 8; ++j) {
      int p = pg*8 + j;
      int hp = ((p & 7) ^ ((p >> 3) & 7)) << 4;
      f16x8 st;
      #pragma unroll
      for (int c = 0; c < 8; ++c) {
        float av = 0.f;
        #pragma unroll
        for (int d = 0; d < 8; ++d) av += a[c][d] * (float)vv[d][j];
        st[c] = (f16)((float)gg[c][j] * av);
      }
      *(f16x8*)(xs + p*128 + ((hd*16) ^ hp)) = st;
    }
  }
  __syncthreads();

  const int wave = tid >> 6, lane = tid & 63;
  const int n0 = wave * 64;
  const int lr = lane & 15, lg = lane >> 4;

  f32x4 acc[4][4];
  #pragma unroll
  for (int i = 0; i < 4; ++i)
    #pragma unroll
    for (int j = 0; j < 4; ++j) acc[i][j] = (f32x4){0.f,0.f,0.f,0.f};

  #pragma unroll
  for (int ks = 0; ks < 2; ++ks) {
    f16x8 af[4], bfr[4];
    #pragma unroll
    for (int mi = 0; mi < 4; ++mi) {
      int m = mi*16 + lr;
      int hm = ((m & 7) ^ ((m >> 3) & 7)) << 4;
      af[mi] = *(const f16x8*)(wl + m*128 + ((ks*64 + lg*16) ^ hm));
    }
    #pragma unroll
    for (int ni = 0; ni < 4; ++ni) {
      int p = n0 + ni*16 + lr;
      int hp = ((p & 7) ^ ((p >> 3) & 7)) << 4;
      bfr[ni] = *(const f16x8*)(xs + p*128 + ((ks*64 + lg*16) ^ hp));
    }
    #pragma unroll
    for (int mi = 0; mi < 4; ++mi)
      #pragma unroll
      for (int ni = 0; ni < 4; ++ni)
        acc[mi][ni] = __builtin_amdgcn_mfma_f32_16x16x32_f16(
            af[mi], bfr[ni], acc[mi][ni], 0, 0, 0);
  }

  const long long obase = (long long)b*64*HW + (long long)y*256;
  #pragma unroll
  for (int mi = 0; mi < 4; ++mi)
    #pragma unroll
    for (int ni = 0; ni < 4; ++ni)
      #pragma unroll
      for (int r = 0; r < 4; ++r) {
        int m = mi*16 + lg*4 + r;
        int p = n0 + ni*16 + lr;
        out[obase + (long long)m*HW + p] = acc[mi][ni][r];
      }
}

// ---------------------------------------------------------------------------
extern "C" void kernel_launch(void* const* d_in, const int* in_sizes, int n_in,
                              void* d_out, int out_size, void* d_ws, size_t ws_size,
                              hipStream_t stream)
{
  float* out = (float*)d_out;

  int mp[7] = {-1,-1,-1,-1,-1,-1,-1};
  bool ok = (n_in == 7);
  if (ok) {
    int n4 = 0;
    for (int i = 0; i < 7; ++i) {
      long s = in_sizes[i];
      if      (s == 33554432) mp[0] = i;            // x
      else if (s == 576)      mp[2] = i;            // w_gate_dw
      else if (s == 12288)    mp[3] = i;            // w_qkv
      else if (s == 1728)     mp[4] = i;            // w_qkv_dw
      else if (s == 8)        mp[6] = i;            // temperature
      else if (s == 4096)     { if (n4 == 0) mp[1] = i; else mp[5] = i; ++n4; }
    }
    ok = ok && (n4 == 2);
    for (int i = 0; i < 7; ++i) ok = ok && (mp[i] >= 0);
  }
  if (!ok) { k_signal<<<2048,256,0,stream>>>(out, (long long)out_size, 2000.0f); return; }
  if (out_size != 33554432) { k_signal<<<2048,256,0,stream>>>(out, (long long)out_size, 3000.0f); return; }

  const float* x    = (const float*)d_in[mp[0]];
  const float* wg   = (const float*)d_in[mp[1]];
  const float* wgd  = (const float*)d_in[mp[2]];
  const float* wqkv = (const float*)d_in[mp[3]];
  const float* wqd  = (const float*)d_in[mp[4]];
  const float* wpj  = (const float*)d_in[mp[5]];
  const float* tp   = (const float*)d_in[mp[6]];

  unsigned char* ws = (unsigned char*)d_ws;
  const size_t GRP_SZ   = 8UL*8*NBAND*80*4;            // 655,360
  const size_t FULL     = 402653184UL + GRP_SZ + 16384UL + 32768UL;
  const size_t PERB_GRP = 8UL*NBAND*80*4;              // 81,920
  const size_t PERB     = 50331648UL + PERB_GRP + 2048UL + 32768UL;

  if (ws != nullptr && ws_size >= FULL) {
    f16*   A    = (f16*)ws;
    f16*   Vv   = (f16*)(ws + 268435456UL);
    f16*   GG   = (f16*)(ws + 335544320UL);
    float* GRP  = (float*)(ws + 402653184UL);
    float* ATT  = (float*)(ws + 402653184UL + GRP_SZ);
    f16*   W16  = (f16*)(ws + 402653184UL + GRP_SZ + 16384UL);
    k0_wconv<<<16,   256, 0, stream>>>(wg, wqkv, W16);
    k1_mfma <<<2048, 256, 0, stream>>>(x, W16, A);
    k2a_dw  <<<4096, 256, 0, stream>>>(A, wgd, wqd, Vv, GG);
    k2b_qk  <<<8*8*NBAND, 64, 0, stream>>>(A, wqd, GRP);
    k2c_attn<<<64,   64,  0, stream>>>(GRP, tp, ATT);
    k3_out  <<<2048, 256, 0, stream>>>(Vv, GG, ATT, wpj, out);
  } else if (ws != nullptr && ws_size >= PERB) {
    f16*   A    = (f16*)ws;
    f16*   Vv   = (f16*)(ws + 33554432UL);
    f16*   GG   = (f16*)(ws + 41943040UL);
    float* GRP  = (float*)(ws + 50331648UL);
    float* ATT  = (float*)(ws + 50331648UL + PERB_GRP);
    f16*   W16  = (f16*)(ws + 50331648UL + PERB_GRP + 2048UL);
    k0_wconv<<<16, 256, 0, stream>>>(wg, wqkv, W16);
    for (int b = 0; b < 8; ++b) {
      const float* xb = x + (long long)b*64*HW;
      float* ob = out + (long long)b*64*HW;
      k1_mfma <<<256,  256, 0, stream>>>(xb, W16, A);
      k2a_dw  <<<512,  256, 0, stream>>>(A, wgd, wqd, Vv, GG);
      k2b_qk  <<<8*NBAND, 64, 0, stream>>>(A, wqd, GRP);
      k2c_attn<<<8,    64,  0, stream>>>(GRP, tp, ATT);
      k3_out  <<<256,  256, 0, stream>>>(Vv, GG, ATT, wpj, ob);
    }
  } else {
    k_signal<<<2048,256,0,stream>>>(out, (long long)out_size, 1000.0f);
  }
}

// Round 21
// 283.616 us; speedup vs baseline: 1.3337x; 1.0156x over previous
//
#include <hip/hip_runtime.h>

typedef _Float16 f16;
using f16x4 = __attribute__((ext_vector_type(4))) _Float16;
using f16x8 = __attribute__((ext_vector_type(8))) _Float16;
using f32x4 = __attribute__((ext_vector_type(4))) float;

#define HW 65536
#define NBAND 16
#define ROWS 16
#define RS 320   // k2b ring row stride in f16

// own erf (A&S 7.1.26, |err| <= 1.5e-7); __expf is HW v_exp_f32
static __device__ __forceinline__ float my_erf(float v) {
  float x = fabsf(v);
  float t = 1.f / (1.f + 0.3275911f * x);
  float y = t * (0.254829592f + t * (-0.284496736f + t * (1.421413741f
          + t * (-1.453152027f + t * 1.061405429f))));
  float r = 1.f - y * __expf(-x * x);
  return v < 0.f ? -r : r;
}
static __device__ __forceinline__ float my_gelu(float s) {
  return 0.5f * s * (1.f + my_erf(s * 0.70710678118654752f));
}

__global__ void TRA_Attention_15281493639325_kernel() {}

__global__ void k_signal(float* out, long long n, float val) {
  long long i = (long long)blockIdx.x * blockDim.x + threadIdx.x;
  long long stride = (long long)gridDim.x * blockDim.x;
  for (; i < n; i += stride) out[i] = val;
}

// ---------------------------------------------------------------------------
// K0: one-time weight convert f32 -> f16, plain [256 out][64 in] layout.
// ---------------------------------------------------------------------------
__global__ __launch_bounds__(256) void k0_wconv(
    const float* __restrict__ w_gate, const float* __restrict__ w_qkv,
    f16* __restrict__ W16)
{
  int i = blockIdx.x * 256 + threadIdx.x;     // 0..4095, 4 elems each
  int m = i >> 4, kc = i & 15;
  const float* src = (m < 64) ? (w_gate + m*64 + kc*4)
                              : (w_qkv + (m-64)*64 + kc*4);
  float4 f = *(const float4*)src;
  f16x4 pk = { (f16)f.x, (f16)f.y, (f16)f.z, (f16)f.w };
  *(f16x4*)(W16 + m*64 + kc*4) = pk;
}

// ---------------------------------------------------------------------------
// K1 (MFMA f16, T14 pipeline): fused 1x1 conv, 256 out ch.
// Persistent block = TWO image rows (512 pos) = 8 tiles of 64 pos.
// grid = nb*128 -> exactly 4 resident blocks/CU, single residency generation.
// 4-barrier tile isolation per tile (replay-stability proven round 15).
// ---------------------------------------------------------------------------
__global__ __launch_bounds__(256) void k1_mfma(
    const float* __restrict__ x, const f16* __restrict__ W16,
    f16* __restrict__ A)
{
  __shared__ __align__(16) unsigned char xs[8192];    // xT 64 pos x 128B swz
  __shared__ __align__(16) f16 os[256*64];            // epilogue tile 32KB

  const int tid = threadIdx.x, blk = blockIdx.x;
  const int b = blk >> 7;
  const long long row0 = (long long)(blk & 127) * 512;

  const int wave = tid >> 6, lane = tid & 63;
  const int m0 = (wave >> 1) * 128, n0 = (wave & 1) * 32;
  const int lr = lane & 15, lg = lane >> 4;

  float4 pre[4];
  #pragma unroll
  for (int i = 0; i < 4; ++i) {
    int cid = tid + (i << 8), k = cid >> 4, c = cid & 15;
    pre[i] = *(const float4*)(x + ((long long)b*64 + k)*HW + row0 + c*4);
  }

  for (int t = 0; t < 8; ++t) {
    const long long p0 = row0 + t*64;

    #pragma unroll
    for (int i = 0; i < 4; ++i) {
      int cid = tid + (i << 8), k = cid >> 4, c = cid & 15;
      const float* e = (const float*)&pre[i];
      #pragma unroll
      for (int j = 0; j < 4; ++j) {
        int p = c*4 + j;
        int hp = ((p & 7) ^ ((p >> 3) & 7)) << 4;
        *(f16*)(xs + p*128 + ((2*k) ^ hp)) = (f16)e[j];
      }
    }
    __syncthreads();                       // barrier 1: xs ready

    if (t < 7) {                           // issue next-tile loads EARLY (T14)
      const long long pn = row0 + (t+1)*64;
      #pragma unroll
      for (int i = 0; i < 4; ++i) {
        int cid = tid + (i << 8), k = cid >> 4, c = cid & 15;
        pre[i] = *(const float4*)(x + ((long long)b*64 + k)*HW + pn + c*4);
      }
    }

    f32x4 acc[8][2];
    #pragma unroll
    for (int i = 0; i < 8; ++i)
      #pragma unroll
      for (int j = 0; j < 2; ++j) acc[i][j] = (f32x4){0.f,0.f,0.f,0.f};

    #pragma unroll
    for (int ks = 0; ks < 2; ++ks) {
      f16x8 af[8], bfr[2];
      #pragma unroll
      for (int mi = 0; mi < 8; ++mi) {
        int m = m0 + mi*16 + lr;
        af[mi] = *(const f16x8*)(W16 + m*64 + ks*32 + lg*8);  // L1-hot
      }
      #pragma unroll
      for (int ni = 0; ni < 2; ++ni) {
        int p = n0 + ni*16 + lr;
        int hp = ((p & 7) ^ ((p >> 3) & 7)) << 4;
        bfr[ni] = *(const f16x8*)(xs + p*128 + ((ks*64 + lg*16) ^ hp));
      }
      #pragma unroll
      for (int mi = 0; mi < 8; ++mi)
        #pragma unroll
        for (int ni = 0; ni < 2; ++ni)
          acc[mi][ni] = __builtin_amdgcn_mfma_f32_16x16x32_f16(
              af[mi], bfr[ni], acc[mi][ni], 0, 0, 0);
    }
    __syncthreads();                       // barrier 2: xs reads done

    #pragma unroll
    for (int mi = 0; mi < 8; ++mi)
      #pragma unroll
      for (int ni = 0; ni < 2; ++ni)
        #pragma unroll
        for (int r = 0; r < 4; ++r) {
          int m = m0 + mi*16 + lg*4 + r;
          int p = n0 + ni*16 + lr;
          os[m*64 + (p ^ ((m & 7) << 3))] = (f16)acc[mi][ni][r];
        }
    __syncthreads();                       // barrier 3: os written

    #pragma unroll
    for (int pass = 0; pass < 8; ++pass) {
      int idx = pass*256 + tid;
      int row = idx >> 3, c8 = idx & 7;
      f16x8 v = *(const f16x8*)((const unsigned char*)os + row*128
                                + ((c8 ^ (row & 7)) * 16));
      *(f16x8*)(A + ((long long)b*256 + row)*HW + p0 + c8*8) = v;
    }
    __syncthreads();                       // barrier 4: tile isolated
  }
}

// ---------------------------------------------------------------------------
// K2a (reg-rolling, LDS-free): depthwise 3x3 for gate (+GELU) and v channels.
// Channel-major block mapping (L2 locality); 16-row strips per thread
// (halo amp 1.125x, fewer cold-starts). grid = nb*256.
// ---------------------------------------------------------------------------
__global__ __launch_bounds__(256) void k2a_dw(
    const f16* __restrict__ A, const float* __restrict__ w_gate_dw,
    const float* __restrict__ w_qkv_dw, f16* __restrict__ Vv, f16* __restrict__ GG)
{
  const int tid = threadIdx.x, blk = blockIdx.x;
  const int yband = blk & 1, ch2 = (blk >> 1) & 127, b = blk >> 8;
  const bool isv = ch2 >= 64;
  const int c = isv ? ch2 - 64 : ch2;
  const f16* src = A + ((long long)b*256 + (isv ? 192 + c : c)) * HW;
  const float* wsrc = isv ? (w_qkv_dw + (128 + c)*9) : (w_gate_dw + c*9);
  f16* dst = (isv ? Vv : GG) + ((long long)b*64 + c) * HW;

  float wd[9];
  #pragma unroll
  for (int j = 0; j < 9; ++j) wd[j] = wsrc[j];

  const int xc = tid & 31, ysub = tid >> 5;
  const int lane = tid & 63;
  const int xbase = xc * 8;
  const int y0 = yband * 128 + ysub * 16;

  float rb[3][10];

  auto load_row = [&](int y, float* r) {
    if (y >= 0 && y < 256) {
      uint4 raw = *(const uint4*)(src + y*256 + xbase);
      const f16* e = (const f16*)&raw;
      #pragma unroll
      for (int t = 0; t < 8; ++t) r[1 + t] = (float)e[t];
    } else {
      #pragma unroll
      for (int t = 0; t < 8; ++t) r[1 + t] = 0.f;
    }
    float lf = __shfl(r[8], lane - 1);
    float rf = __shfl(r[1], lane + 1);
    r[0] = (xc == 0)  ? 0.f : lf;
    r[9] = (xc == 31) ? 0.f : rf;
  };

  load_row(y0 - 1, rb[0]);
  load_row(y0,     rb[1]);

  #pragma unroll
  for (int i = 0; i < 16; ++i) {
    load_row(y0 + i + 1, rb[(i + 2) % 3]);
    const float* rm = rb[i % 3];
    const float* r0 = rb[(i + 1) % 3];
    const float* rp = rb[(i + 2) % 3];
    f16x8 st;
    #pragma unroll
    for (int j = 0; j < 8; ++j) {
      float s = wd[0]*rm[j] + wd[1]*rm[j+1] + wd[2]*rm[j+2]
              + wd[3]*r0[j] + wd[4]*r0[j+1] + wd[5]*r0[j+2]
              + wd[6]*rp[j] + wd[7]*rp[j+1] + wd[8]*rp[j+2];
      if (!isv) s = my_gelu(s);
      st[j] = (f16)s;
    }
    *(f16x8*)(dst + (y0 + i)*256 + xbase) = st;
  }
}

// ---------------------------------------------------------------------------
// K2b (MFMA gram, ring + wide reads): dwconv for q,k of one head fused with
// the 16x16 gram via mfma_f32_16x16x32_f16 (identical A/B fragments).
// Ring staging/prefetch/barriers = round-15 (proven stable); b128 reads +
// __shfl x-halos = round-17 (proven). 1 wave per (b,h,16-row band).
// GRP: [b][h][band][80] = qq[8], kk[8], qk[64].
// ---------------------------------------------------------------------------
__device__ __forceinline__ int ridx(int c, int slot, int i) {
  return ((((c << 2) | slot) * RS) + i) ^ ((c & 7) << 3);
}

__global__ __launch_bounds__(64) void k2b_qk(
    const f16* __restrict__ A, const float* __restrict__ w_qkv_dw,
    float* __restrict__ GRP)
{
  __shared__ __align__(16) f16 ring[16*4*RS];
  const int lane = threadIdx.x, blk = blockIdx.x;
  const int band = blk & (NBAND-1), h = (blk >> 4) & 7, b = blk >> 7;

  const int c  = lane & 15, g  = lane >> 4;   // compute role
  const int cs = lane >> 2, q4 = lane & 3;    // staging role

  const int wrow = (c < 8) ? (h*8 + c) : (64 + h*8 + (c - 8));
  float wq[9];
  #pragma unroll
  for (int j = 0; j < 9; ++j) wq[j] = w_qkv_dw[wrow*9 + j];

  const f16* sbase = A + ((long long)b*256 +
      (cs < 8 ? 64 + h*8 + cs : 128 + h*8 + (cs - 8))) * HW;

  auto load_row = [&](int yy, uint4* r) {
    if (yy >= 0 && yy < 256) {
      const f16* p = sbase + yy*256 + q4*64;
      #pragma unroll
      for (int t = 0; t < 8; ++t) r[t] = *(const uint4*)(p + t*8);
    } else {
      #pragma unroll
      for (int t = 0; t < 8; ++t) r[t] = make_uint4(0u,0u,0u,0u);
    }
  };
  auto write_row = [&](int slot, const uint4* r) {
    #pragma unroll
    for (int t = 0; t < 8; ++t)
      *(uint4*)&ring[ridx(cs, slot, 8 + q4*64 + t*8)] = r[t];
  };

  auto conv_accum = [&](const f16x8* R, const float* w, float* fr, int q) {
    float v[10];
    #pragma unroll
    for (int t = 0; t < 8; ++t) v[1 + t] = (float)R[q][t];
    float e7p = (q > 0) ? (float)R[q-1][7] : 0.f;
    float e0n = (q < 7) ? (float)R[q+1][0] : 0.f;
    float L1 = __shfl(v[8], lane - 16);          // (c,g-1) chunk q, e7
    float L2 = __shfl(e7p, (lane & 15) + 48);    // (c,3) chunk q-1, e7
    float Q1 = __shfl(v[1], lane + 16);          // (c,g+1) chunk q, e0
    float Q2 = __shfl(e0n, lane & 15);           // (c,0) chunk q+1, e0
    v[0] = (g > 0) ? L1 : ((q > 0) ? L2 : 0.f);
    v[9] = (g < 3) ? Q1 : ((q < 7) ? Q2 : 0.f);
    #pragma unroll
    for (int j = 0; j < 8; ++j)
      fr[j] += w[0]*v[j] + w[1]*v[j+1] + w[2]*v[j+2];
  };

  f32x4 acc = (f32x4){0.f, 0.f, 0.f, 0.f};

  const int y0 = band * ROWS;
  {
    uint4 r[8];
    load_row(y0-1, r); write_row((y0+3)&3, r);
    load_row(y0,   r); write_row((y0+4)&3, r);
    load_row(y0+1, r); write_row((y0+5)&3, r);
  }
  __syncthreads();

  for (int y = y0; y < y0 + ROWS; ++y) {
    uint4 r[8];
    const bool pf = (y + 2 <= y0 + ROWS);
    if (pf) load_row(y + 2, r);              // issue early (T14)

    const int s0 = (y+3)&3, s1 = (y+4)&3, s2 = (y+5)&3;
    f16x8 Rm[8], Rc[8], Rp[8];
    #pragma unroll
    for (int q = 0; q < 8; ++q) {
      Rm[q] = *(const f16x8*)&ring[ridx(c, s0, 8 + q*32 + g*8)];
      Rc[q] = *(const f16x8*)&ring[ridx(c, s1, 8 + q*32 + g*8)];
      Rp[q] = *(const f16x8*)&ring[ridx(c, s2, 8 + q*32 + g*8)];
    }

    #pragma unroll
    for (int q = 0; q < 8; ++q) {
      float fr[8] = {0.f,0.f,0.f,0.f,0.f,0.f,0.f,0.f};
      conv_accum(Rm, wq + 0, fr, q);
      conv_accum(Rc, wq + 3, fr, q);
      conv_accum(Rp, wq + 6, fr, q);
      f16x8 frag;
      #pragma unroll
      for (int j = 0; j < 8; ++j) frag[j] = (f16)fr[j];
      acc = __builtin_amdgcn_mfma_f32_16x16x32_f16(frag, frag, acc, 0, 0, 0);
    }

    if (pf) write_row((y+6)&3, r);           // write late, after reads
    __syncthreads();
  }

  const long long gbase = (long long)((b*8 + h)*NBAND + band) * 80;
  #pragma unroll
  for (int reg = 0; reg < 4; ++reg) {
    int rrow = g*4 + reg;
    float val = acc[reg];
    if (rrow == c) GRP[gbase + c] = val;
    else if (rrow < 8 && c >= 8) GRP[gbase + 16 + rrow*8 + (c-8)] = val;
  }
}

// ---------------------------------------------------------------------------
// K2c: reduce band partials, normalize, temperature, softmax. grid = nb*8
// ---------------------------------------------------------------------------
__global__ __launch_bounds__(64) void k2c_attn(
    const float* __restrict__ GRP, const float* __restrict__ temp,
    float* __restrict__ ATT)
{
  __shared__ float s[80];
  const int tid = threadIdx.x;
  const int h = blockIdx.x & 7, b = blockIdx.x >> 3;
  for (int i = tid; i < 80; i += 64) {
    float v = 0.f;
    for (int band = 0; band < NBAND; ++band)
      v += GRP[(((b*8 + h)*NBAND + band) * 80) + i];
    s[i] = v;
  }
  __syncthreads();
  const int c = tid >> 3, d = tid & 7;
  float nq = fmaxf(sqrtf(s[c]), 1e-12f);
  float nk = fmaxf(sqrtf(s[8 + d]), 1e-12f);
  float logit = s[16 + c*8 + d] / (nq * nk) * temp[h];
  float m = logit;
  #pragma unroll
  for (int off = 4; off; off >>= 1) m = fmaxf(m, __shfl_xor(m, off));
  float e = __expf(logit - m);
  float sum = e;
  #pragma unroll
  for (int off = 4; off; off >>= 1) sum += __shfl_xor(sum, off);
  ATT[((b*8 + h)*8 + c)*8 + d] = e / sum;
}

// ---------------------------------------------------------------------------
// K3 (MFMA proj): g = gelu(gate)*(attn@v) -> f16 LDS tile -> MFMA with
// w_proj (f16) -> f32 out. Block = 256 thr, one image row (256 pos).
// grid = nb*256.
// ---------------------------------------------------------------------------
__global__ __launch_bounds__(256) void k3_out(
    const f16* __restrict__ Vv, const f16* __restrict__ GG,
    const float* __restrict__ ATT, const float* __restrict__ w_proj,
    float* __restrict__ out)
{
  __shared__ __align__(16) unsigned char lds[64*128 + 256*128 + 2048];
  unsigned char* wl = lds;                    // wp f16 [64co][64ch] swz rows
  unsigned char* xs = lds + 64*128;           // g  f16 [256pos][64ch] swz rows
  float* attn_s = (float*)(lds + 64*128 + 256*128);

  const int tid = threadIdx.x;
  const int y = blockIdx.x & 255, b = blockIdx.x >> 8;

  for (int cid = tid; cid < 1024; cid += 256) {
    int m = cid >> 4, kc = cid & 15;
    float4 f = *(const float4*)(w_proj + m*64 + kc*4);
    int hm = ((m & 7) ^ ((m >> 3) & 7)) << 4;
    f16x4 pk = { (f16)f.x, (f16)f.y, (f16)f.z, (f16)f.w };
    *(f16x4*)(wl + m*128 + ((kc*8) ^ hm)) = pk;
  }
  for (int i = tid; i < 512; i += 256) attn_s[i] = ATT[b*512 + i];
  __syncthreads();

  {
    const int pg = tid & 31, hd = tid >> 5;
    const long long base = ((long long)b*64 + hd*8)*HW + (long long)y*256 + pg*8;
    f16x8 vv[8], gg[8];
    #pragma unroll
    for (int d = 0; d < 8; ++d)
      vv[d] = *(const f16x8*)(Vv + base + (long long)d*HW);
    #pragma unroll
    for (int c = 0; c < 8; ++c)
      gg[c] = *(const f16x8*)(GG + base + (long long)c*HW);
    float a[8][8];
    #pragma unroll
    for (int c = 0; c < 8; ++c)
      #pragma unroll
      for (int d = 0; d < 8; ++d) a[c][d] = attn_s[hd*64 + c*8 + d];
    #pragma unroll
    for (int j = 0; j < 8; ++j) {
      int p = pg*8 + j;
      int hp = ((p & 7) ^ ((p >> 3) & 7)) << 4;
      f16x8 st;
      #pragma unroll
      for (int c = 0; c < 8; ++c) {
        float av = 0.f;
        #pragma unroll
        for (int d = 0; d < 8; ++d) av += a[c][d] * (float)vv[d][j];
        st[c] = (f16)((float)gg[c][j] * av);
      }
      *(f16x8*)(xs + p*128 + ((hd*16) ^ hp)) = st;
    }
  }
  __syncthreads();

  const int wave = tid >> 6, lane = tid & 63;
  const int n0 = wave * 64;
  const int lr = lane & 15, lg = lane >> 4;

  f32x4 acc[4][4];
  #pragma unroll
  for (int i = 0; i < 4; ++i)
    #pragma unroll
    for (int j = 0; j < 4; ++j) acc[i][j] = (f32x4){0.f,0.f,0.f,0.f};

  #pragma unroll
  for (int ks = 0; ks < 2; ++ks) {
    f16x8 af[4], bfr[4];
    #pragma unroll
    for (int mi = 0; mi < 4; ++mi) {
      int m = mi*16 + lr;
      int hm = ((m & 7) ^ ((m >> 3) & 7)) << 4;
      af[mi] = *(const f16x8*)(wl + m*128 + ((ks*64 + lg*16) ^ hm));
    }
    #pragma unroll
    for (int ni = 0; ni < 4; ++ni) {
      int p = n0 + ni*16 + lr;
      int hp = ((p & 7) ^ ((p >> 3) & 7)) << 4;
      bfr[ni] = *(const f16x8*)(xs + p*128 + ((ks*64 + lg*16) ^ hp));
    }
    #pragma unroll
    for (int mi = 0; mi < 4; ++mi)
      #pragma unroll
      for (int ni = 0; ni < 4; ++ni)
        acc[mi][ni] = __builtin_amdgcn_mfma_f32_16x16x32_f16(
            af[mi], bfr[ni], acc[mi][ni], 0, 0, 0);
  }

  const long long obase = (long long)b*64*HW + (long long)y*256;
  #pragma unroll
  for (int mi = 0; mi < 4; ++mi)
    #pragma unroll
    for (int ni = 0; ni < 4; ++ni)
      #pragma unroll
      for (int r = 0; r < 4; ++r) {
        int m = mi*16 + lg*4 + r;
        int p = n0 + ni*16 + lr;
        out[obase + (long long)m*HW + p] = acc[mi][ni][r];
      }
}

// ---------------------------------------------------------------------------
extern "C" void kernel_launch(void* const* d_in, const int* in_sizes, int n_in,
                              void* d_out, int out_size, void* d_ws, size_t ws_size,
                              hipStream_t stream)
{
  float* out = (float*)d_out;

  int mp[7] = {-1,-1,-1,-1,-1,-1,-1};
  bool ok = (n_in == 7);
  if (ok) {
    int n4 = 0;
    for (int i = 0; i < 7; ++i) {
      long s = in_sizes[i];
      if      (s == 33554432) mp[0] = i;            // x
      else if (s == 576)      mp[2] = i;            // w_gate_dw
      else if (s == 12288)    mp[3] = i;            // w_qkv
      else if (s == 1728)     mp[4] = i;            // w_qkv_dw
      else if (s == 8)        mp[6] = i;            // temperature
      else if (s == 4096)     { if (n4 == 0) mp[1] = i; else mp[5] = i; ++n4; }
    }
    ok = ok && (n4 == 2);
    for (int i = 0; i < 7; ++i) ok = ok && (mp[i] >= 0);
  }
  if (!ok) { k_signal<<<2048,256,0,stream>>>(out, (long long)out_size, 2000.0f); return; }
  if (out_size != 33554432) { k_signal<<<2048,256,0,stream>>>(out, (long long)out_size, 3000.0f); return; }

  const float* x    = (const float*)d_in[mp[0]];
  const float* wg   = (const float*)d_in[mp[1]];
  const float* wgd  = (const float*)d_in[mp[2]];
  const float* wqkv = (const float*)d_in[mp[3]];
  const float* wqd  = (const float*)d_in[mp[4]];
  const float* wpj  = (const float*)d_in[mp[5]];
  const float* tp   = (const float*)d_in[mp[6]];

  unsigned char* ws = (unsigned char*)d_ws;
  const size_t GRP_SZ   = 8UL*8*NBAND*80*4;            // 327,680
  const size_t FULL     = 402653184UL + GRP_SZ + 16384UL + 32768UL;
  const size_t PERB_GRP = 8UL*NBAND*80*4;              // 40,960
  const size_t PERB     = 50331648UL + PERB_GRP + 2048UL + 32768UL;

  if (ws != nullptr && ws_size >= FULL) {
    f16*   A    = (f16*)ws;
    f16*   Vv   = (f16*)(ws + 268435456UL);
    f16*   GG   = (f16*)(ws + 335544320UL);
    float* GRP  = (float*)(ws + 402653184UL);
    float* ATT  = (float*)(ws + 402653184UL + GRP_SZ);
    f16*   W16  = (f16*)(ws + 402653184UL + GRP_SZ + 16384UL);
    k0_wconv<<<16,   256, 0, stream>>>(wg, wqkv, W16);
    k1_mfma <<<1024, 256, 0, stream>>>(x, W16, A);
    k2a_dw  <<<2048, 256, 0, stream>>>(A, wgd, wqd, Vv, GG);
    k2b_qk  <<<8*8*NBAND, 64, 0, stream>>>(A, wqd, GRP);
    k2c_attn<<<64,   64,  0, stream>>>(GRP, tp, ATT);
    k3_out  <<<2048, 256, 0, stream>>>(Vv, GG, ATT, wpj, out);
  } else if (ws != nullptr && ws_size >= PERB) {
    f16*   A    = (f16*)ws;
    f16*   Vv   = (f16*)(ws + 33554432UL);
    f16*   GG   = (f16*)(ws + 41943040UL);
    float* GRP  = (float*)(ws + 50331648UL);
    float* ATT  = (float*)(ws + 50331648UL + PERB_GRP);
    f16*   W16  = (f16*)(ws + 50331648UL + PERB_GRP + 2048UL);
    k0_wconv<<<16, 256, 0, stream>>>(wg, wqkv, W16);
    for (int b = 0; b < 8; ++b) {
      const float* xb = x + (long long)b*64*HW;
      float* ob = out + (long long)b*64*HW;
      k1_mfma <<<128,  256, 0, stream>>>(xb, W16, A);
      k2a_dw  <<<256,  256, 0, stream>>>(A, wgd, wqd, Vv, GG);
      k2b_qk  <<<8*NBAND, 64, 0, stream>>>(A, wqd, GRP);
      k2c_attn<<<8,    64,  0, stream>>>(GRP, tp, ATT);
      k3_out  <<<256,  256, 0, stream>>>(Vv, GG, ATT, wpj, ob);
    }
  } else {
    k_signal<<<2048,256,0,stream>>>(out, (long long)out_size, 1000.0f);
  }
}

// Round 22
// 270.473 us; speedup vs baseline: 1.3985x; 1.0486x over previous
//
#include <hip/hip_runtime.h>

typedef _Float16 f16;
using f16x4 = __attribute__((ext_vector_type(4))) _Float16;
using f16x8 = __attribute__((ext_vector_type(8))) _Float16;
using f32x4 = __attribute__((ext_vector_type(4))) float;

#define HW 65536
#define NBAND 16
#define ROWS 16
#define RS 320   // k2b ring row stride in f16

// own erf (A&S 7.1.26, |err| <= 1.5e-7); __expf is HW v_exp_f32
static __device__ __forceinline__ float my_erf(float v) {
  float x = fabsf(v);
  float t = 1.f / (1.f + 0.3275911f * x);
  float y = t * (0.254829592f + t * (-0.284496736f + t * (1.421413741f
          + t * (-1.453152027f + t * 1.061405429f))));
  float r = 1.f - y * __expf(-x * x);
  return v < 0.f ? -r : r;
}
static __device__ __forceinline__ float my_gelu(float s) {
  return 0.5f * s * (1.f + my_erf(s * 0.70710678118654752f));
}

__global__ void TRA_Attention_15281493639325_kernel() {}

__global__ void k_signal(float* out, long long n, float val) {
  long long i = (long long)blockIdx.x * blockDim.x + threadIdx.x;
  long long stride = (long long)gridDim.x * blockDim.x;
  for (; i < n; i += stride) out[i] = val;
}

// ---------------------------------------------------------------------------
// K0: one-time weight convert f32 -> f16, plain [256 out][64 in] layout.
// ---------------------------------------------------------------------------
__global__ __launch_bounds__(256) void k0_wconv(
    const float* __restrict__ w_gate, const float* __restrict__ w_qkv,
    f16* __restrict__ W16)
{
  int i = blockIdx.x * 256 + threadIdx.x;     // 0..4095, 4 elems each
  int m = i >> 4, kc = i & 15;
  const float* src = (m < 64) ? (w_gate + m*64 + kc*4)
                              : (w_qkv + (m-64)*64 + kc*4);
  float4 f = *(const float4*)src;
  f16x4 pk = { (f16)f.x, (f16)f.y, (f16)f.z, (f16)f.w };
  *(f16x4*)(W16 + m*64 + kc*4) = pk;
}

// ---------------------------------------------------------------------------
// K1 (MFMA f16, T14 pipeline): fused 1x1 conv, 256 out ch.
// Persistent block = one image row (256 pos) = 4 tiles of 64 pos.
// 4-barrier tile isolation (replay-stability proven round 15 — do not relax).
// ---------------------------------------------------------------------------
__global__ __launch_bounds__(256) void k1_mfma(
    const float* __restrict__ x, const f16* __restrict__ W16,
    f16* __restrict__ A)
{
  __shared__ __align__(16) unsigned char xs[8192];    // xT 64 pos x 128B swz
  __shared__ __align__(16) f16 os[256*64];            // epilogue tile 32KB

  const int tid = threadIdx.x, blk = blockIdx.x;
  const int b = blk >> 8;
  const long long row0 = (long long)(blk & 255) * 256;

  const int wave = tid >> 6, lane = tid & 63;
  const int m0 = (wave >> 1) * 128, n0 = (wave & 1) * 32;
  const int lr = lane & 15, lg = lane >> 4;

  float4 pre[4];
  #pragma unroll
  for (int i = 0; i < 4; ++i) {
    int cid = tid + (i << 8), k = cid >> 4, c = cid & 15;
    pre[i] = *(const float4*)(x + ((long long)b*64 + k)*HW + row0 + c*4);
  }

  for (int t = 0; t < 4; ++t) {
    const long long p0 = row0 + t*64;

    #pragma unroll
    for (int i = 0; i < 4; ++i) {
      int cid = tid + (i << 8), k = cid >> 4, c = cid & 15;
      const float* e = (const float*)&pre[i];
      #pragma unroll
      for (int j = 0; j < 4; ++j) {
        int p = c*4 + j;
        int hp = ((p & 7) ^ ((p >> 3) & 7)) << 4;
        *(f16*)(xs + p*128 + ((2*k) ^ hp)) = (f16)e[j];
      }
    }
    __syncthreads();                       // barrier 1: xs ready

    if (t < 3) {                           // issue next-tile loads EARLY (T14)
      const long long pn = row0 + (t+1)*64;
      #pragma unroll
      for (int i = 0; i < 4; ++i) {
        int cid = tid + (i << 8), k = cid >> 4, c = cid & 15;
        pre[i] = *(const float4*)(x + ((long long)b*64 + k)*HW + pn + c*4);
      }
    }

    f32x4 acc[8][2];
    #pragma unroll
    for (int i = 0; i < 8; ++i)
      #pragma unroll
      for (int j = 0; j < 2; ++j) acc[i][j] = (f32x4){0.f,0.f,0.f,0.f};

    #pragma unroll
    for (int ks = 0; ks < 2; ++ks) {
      f16x8 af[8], bfr[2];
      #pragma unroll
      for (int mi = 0; mi < 8; ++mi) {
        int m = m0 + mi*16 + lr;
        af[mi] = *(const f16x8*)(W16 + m*64 + ks*32 + lg*8);  // L1-hot
      }
      #pragma unroll
      for (int ni = 0; ni < 2; ++ni) {
        int p = n0 + ni*16 + lr;
        int hp = ((p & 7) ^ ((p >> 3) & 7)) << 4;
        bfr[ni] = *(const f16x8*)(xs + p*128 + ((ks*64 + lg*16) ^ hp));
      }
      #pragma unroll
      for (int mi = 0; mi < 8; ++mi)
        #pragma unroll
        for (int ni = 0; ni < 2; ++ni)
          acc[mi][ni] = __builtin_amdgcn_mfma_f32_16x16x32_f16(
              af[mi], bfr[ni], acc[mi][ni], 0, 0, 0);
    }
    __syncthreads();                       // barrier 2: xs reads done

    #pragma unroll
    for (int mi = 0; mi < 8; ++mi)
      #pragma unroll
      for (int ni = 0; ni < 2; ++ni)
        #pragma unroll
        for (int r = 0; r < 4; ++r) {
          int m = m0 + mi*16 + lg*4 + r;
          int p = n0 + ni*16 + lr;
          os[m*64 + (p ^ ((m & 7) << 3))] = (f16)acc[mi][ni][r];
        }
    __syncthreads();                       // barrier 3: os written

    #pragma unroll
    for (int pass = 0; pass < 8; ++pass) {
      int idx = pass*256 + tid;
      int row = idx >> 3, c8 = idx & 7;
      f16x8 v = *(const f16x8*)((const unsigned char*)os + row*128
                                + ((c8 ^ (row & 7)) * 16));
      *(f16x8*)(A + ((long long)b*256 + row)*HW + p0 + c8*8) = v;
    }
    __syncthreads();                       // barrier 4: tile isolated
  }
}

// ---------------------------------------------------------------------------
// K2a (reg-rolling, LDS-free): depthwise 3x3 for gate (+GELU) and v channels.
// Channel-major mapping, 8-row strips, 32 VGPR / 73% occupancy (round-17
// proven fastest variant — prefetch and remap variants both regressed).
// grid = nb*512.
// ---------------------------------------------------------------------------
__global__ __launch_bounds__(256) void k2a_dw(
    const f16* __restrict__ A, const float* __restrict__ w_gate_dw,
    const float* __restrict__ w_qkv_dw, f16* __restrict__ Vv, f16* __restrict__ GG)
{
  const int tid = threadIdx.x, blk = blockIdx.x;
  const int yband = blk & 3, ch2 = (blk >> 2) & 127, b = blk >> 9;
  const bool isv = ch2 >= 64;
  const int c = isv ? ch2 - 64 : ch2;
  const f16* src = A + ((long long)b*256 + (isv ? 192 + c : c)) * HW;
  const float* wsrc = isv ? (w_qkv_dw + (128 + c)*9) : (w_gate_dw + c*9);
  f16* dst = (isv ? Vv : GG) + ((long long)b*64 + c) * HW;

  float wd[9];
  #pragma unroll
  for (int j = 0; j < 9; ++j) wd[j] = wsrc[j];

  const int xc = tid & 31, ysub = tid >> 5;
  const int lane = tid & 63;
  const int xbase = xc * 8;
  const int y0 = yband * 64 + ysub * 8;

  float rb[3][10];

  auto load_row = [&](int y, float* r) {
    if (y >= 0 && y < 256) {
      uint4 raw = *(const uint4*)(src + y*256 + xbase);
      const f16* e = (const f16*)&raw;
      #pragma unroll
      for (int t = 0; t < 8; ++t) r[1 + t] = (float)e[t];
    } else {
      #pragma unroll
      for (int t = 0; t < 8; ++t) r[1 + t] = 0.f;
    }
    float lf = __shfl(r[8], lane - 1);
    float rf = __shfl(r[1], lane + 1);
    r[0] = (xc == 0)  ? 0.f : lf;
    r[9] = (xc == 31) ? 0.f : rf;
  };

  load_row(y0 - 1, rb[0]);
  load_row(y0,     rb[1]);

  #pragma unroll
  for (int i = 0; i < 8; ++i) {
    load_row(y0 + i + 1, rb[(i + 2) % 3]);
    const float* rm = rb[i % 3];
    const float* r0 = rb[(i + 1) % 3];
    const float* rp = rb[(i + 2) % 3];
    f16x8 st;
    #pragma unroll
    for (int j = 0; j < 8; ++j) {
      float s = wd[0]*rm[j] + wd[1]*rm[j+1] + wd[2]*rm[j+2]
              + wd[3]*r0[j] + wd[4]*r0[j+1] + wd[5]*r0[j+2]
              + wd[6]*rp[j] + wd[7]*rp[j+1] + wd[8]*rp[j+2];
      if (!isv) s = my_gelu(s);
      st[j] = (f16)s;
    }
    *(f16x8*)(dst + (y0 + i)*256 + xbase) = st;
  }
}

// ---------------------------------------------------------------------------
// K2b (MFMA gram, ring + wide reads): dwconv for q,k of one head fused with
// the 16x16 gram via mfma_f32_16x16x32_f16 (identical A/B fragments).
// Ring staging/prefetch/barriers = round-15 (proven stable); b128 reads +
// __shfl x-halos = round-17 (proven). 1 wave per (b,h,16-row band).
// GRP: [b][h][band][80] = qq[8], kk[8], qk[64].
// ---------------------------------------------------------------------------
__device__ __forceinline__ int ridx(int c, int slot, int i) {
  return ((((c << 2) | slot) * RS) + i) ^ ((c & 7) << 3);
}

__global__ __launch_bounds__(64) void k2b_qk(
    const f16* __restrict__ A, const float* __restrict__ w_qkv_dw,
    float* __restrict__ GRP)
{
  __shared__ __align__(16) f16 ring[16*4*RS];
  const int lane = threadIdx.x, blk = blockIdx.x;
  const int band = blk & (NBAND-1), h = (blk >> 4) & 7, b = blk >> 7;

  const int c  = lane & 15, g  = lane >> 4;   // compute role
  const int cs = lane >> 2, q4 = lane & 3;    // staging role

  const int wrow = (c < 8) ? (h*8 + c) : (64 + h*8 + (c - 8));
  float wq[9];
  #pragma unroll
  for (int j = 0; j < 9; ++j) wq[j] = w_qkv_dw[wrow*9 + j];

  const f16* sbase = A + ((long long)b*256 +
      (cs < 8 ? 64 + h*8 + cs : 128 + h*8 + (cs - 8))) * HW;

  auto load_row = [&](int yy, uint4* r) {
    if (yy >= 0 && yy < 256) {
      const f16* p = sbase + yy*256 + q4*64;
      #pragma unroll
      for (int t = 0; t < 8; ++t) r[t] = *(const uint4*)(p + t*8);
    } else {
      #pragma unroll
      for (int t = 0; t < 8; ++t) r[t] = make_uint4(0u,0u,0u,0u);
    }
  };
  auto write_row = [&](int slot, const uint4* r) {
    #pragma unroll
    for (int t = 0; t < 8; ++t)
      *(uint4*)&ring[ridx(cs, slot, 8 + q4*64 + t*8)] = r[t];
  };

  auto conv_accum = [&](const f16x8* R, const float* w, float* fr, int q) {
    float v[10];
    #pragma unroll
    for (int t = 0; t < 8; ++t) v[1 + t] = (float)R[q][t];
    float e7p = (q > 0) ? (float)R[q-1][7] : 0.f;
    float e0n = (q < 7) ? (float)R[q+1][0] : 0.f;
    float L1 = __shfl(v[8], lane - 16);          // (c,g-1) chunk q, e7
    float L2 = __shfl(e7p, (lane & 15) + 48);    // (c,3) chunk q-1, e7
    float Q1 = __shfl(v[1], lane + 16);          // (c,g+1) chunk q, e0
    float Q2 = __shfl(e0n, lane & 15);           // (c,0) chunk q+1, e0
    v[0] = (g > 0) ? L1 : ((q > 0) ? L2 : 0.f);
    v[9] = (g < 3) ? Q1 : ((q < 7) ? Q2 : 0.f);
    #pragma unroll
    for (int j = 0; j < 8; ++j)
      fr[j] += w[0]*v[j] + w[1]*v[j+1] + w[2]*v[j+2];
  };

  f32x4 acc = (f32x4){0.f, 0.f, 0.f, 0.f};

  const int y0 = band * ROWS;
  {
    uint4 r[8];
    load_row(y0-1, r); write_row((y0+3)&3, r);
    load_row(y0,   r); write_row((y0+4)&3, r);
    load_row(y0+1, r); write_row((y0+5)&3, r);
  }
  __syncthreads();

  for (int y = y0; y < y0 + ROWS; ++y) {
    uint4 r[8];
    const bool pf = (y + 2 <= y0 + ROWS);
    if (pf) load_row(y + 2, r);              // issue early (T14)

    const int s0 = (y+3)&3, s1 = (y+4)&3, s2 = (y+5)&3;
    f16x8 Rm[8], Rc[8], Rp[8];
    #pragma unroll
    for (int q = 0; q < 8; ++q) {
      Rm[q] = *(const f16x8*)&ring[ridx(c, s0, 8 + q*32 + g*8)];
      Rc[q] = *(const f16x8*)&ring[ridx(c, s1, 8 + q*32 + g*8)];
      Rp[q] = *(const f16x8*)&ring[ridx(c, s2, 8 + q*32 + g*8)];
    }

    #pragma unroll
    for (int q = 0; q < 8; ++q) {
      float fr[8] = {0.f,0.f,0.f,0.f,0.f,0.f,0.f,0.f};
      conv_accum(Rm, wq + 0, fr, q);
      conv_accum(Rc, wq + 3, fr, q);
      conv_accum(Rp, wq + 6, fr, q);
      f16x8 frag;
      #pragma unroll
      for (int j = 0; j < 8; ++j) frag[j] = (f16)fr[j];
      acc = __builtin_amdgcn_mfma_f32_16x16x32_f16(frag, frag, acc, 0, 0, 0);
    }

    if (pf) write_row((y+6)&3, r);           // write late, after reads
    __syncthreads();
  }

  const long long gbase = (long long)((b*8 + h)*NBAND + band) * 80;
  #pragma unroll
  for (int reg = 0; reg < 4; ++reg) {
    int rrow = g*4 + reg;
    float val = acc[reg];
    if (rrow == c) GRP[gbase + c] = val;
    else if (rrow < 8 && c >= 8) GRP[gbase + 16 + rrow*8 + (c-8)] = val;
  }
}

// ---------------------------------------------------------------------------
// K2c: reduce band partials, normalize, temperature, softmax. grid = nb*8
// ---------------------------------------------------------------------------
__global__ __launch_bounds__(64) void k2c_attn(
    const float* __restrict__ GRP, const float* __restrict__ temp,
    float* __restrict__ ATT)
{
  __shared__ float s[80];
  const int tid = threadIdx.x;
  const int h = blockIdx.x & 7, b = blockIdx.x >> 3;
  for (int i = tid; i < 80; i += 64) {
    float v = 0.f;
    for (int band = 0; band < NBAND; ++band)
      v += GRP[(((b*8 + h)*NBAND + band) * 80) + i];
    s[i] = v;
  }
  __syncthreads();
  const int c = tid >> 3, d = tid & 7;
  float nq = fmaxf(sqrtf(s[c]), 1e-12f);
  float nk = fmaxf(sqrtf(s[8 + d]), 1e-12f);
  float logit = s[16 + c*8 + d] / (nq * nk) * temp[h];
  float m = logit;
  #pragma unroll
  for (int off = 4; off; off >>= 1) m = fmaxf(m, __shfl_xor(m, off));
  float e = __expf(logit - m);
  float sum = e;
  #pragma unroll
  for (int off = 4; off; off >>= 1) sum += __shfl_xor(sum, off);
  ATT[((b*8 + h)*8 + c)*8 + d] = e / sum;
}

// ---------------------------------------------------------------------------
// K3 (MFMA proj): g = gelu(gate)*(attn@v) -> f16 LDS tile -> MFMA with
// w_proj (f16) -> f32 out. Block = 256 thr, one image row (256 pos).
// grid = nb*256.
// ---------------------------------------------------------------------------
__global__ __launch_bounds__(256) void k3_out(
    const f16* __restrict__ Vv, const f16* __restrict__ GG,
    const float* __restrict__ ATT, const float* __restrict__ w_proj,
    float* __restrict__ out)
{
  __shared__ __align__(16) unsigned char lds[64*128 + 256*128 + 2048];
  unsigned char* wl = lds;                    // wp f16 [64co][64ch] swz rows
  unsigned char* xs = lds + 64*128;           // g  f16 [256pos][64ch] swz rows
  float* attn_s = (float*)(lds + 64*128 + 256*128);

  const int tid = threadIdx.x;
  const int y = blockIdx.x & 255, b = blockIdx.x >> 8;

  for (int cid = tid; cid < 1024; cid += 256) {
    int m = cid >> 4, kc = cid & 15;
    float4 f = *(const float4*)(w_proj + m*64 + kc*4);
    int hm = ((m & 7) ^ ((m >> 3) & 7)) << 4;
    f16x4 pk = { (f16)f.x, (f16)f.y, (f16)f.z, (f16)f.w };
    *(f16x4*)(wl + m*128 + ((kc*8) ^ hm)) = pk;
  }
  for (int i = tid; i < 512; i += 256) attn_s[i] = ATT[b*512 + i];
  __syncthreads();

  {
    const int pg = tid & 31, hd = tid >> 5;
    const long long base = ((long long)b*64 + hd*8)*HW + (long long)y*256 + pg*8;
    f16x8 vv[8], gg[8];
    #pragma unroll
    for (int d = 0; d < 8; ++d)
      vv[d] = *(const f16x8*)(Vv + base + (long long)d*HW);
    #pragma unroll
    for (int c = 0; c < 8; ++c)
      gg[c] = *(const f16x8*)(GG + base + (long long)c*HW);
    float a[8][8];
    #pragma unroll
    for (int c = 0; c < 8; ++c)
      #pragma unroll
      for (int d = 0; d < 8; ++d) a[c][d] = attn_s[hd*64 + c*8 + d];
    #pragma unroll
    for (int j = 0; j < 8; ++j) {
      int p = pg*8 + j;
      int hp = ((p & 7) ^ ((p >> 3) & 7)) << 4;
      f16x8 st;
      #pragma unroll
      for (int c = 0; c < 8; ++c) {
        float av = 0.f;
        #pragma unroll
        for (int d = 0; d < 8; ++d) av += a[c][d] * (float)vv[d][j];
        st[c] = (f16)((float)gg[c][j] * av);
      }
      *(f16x8*)(xs + p*128 + ((hd*16) ^ hp)) = st;
    }
  }
  __syncthreads();

  const int wave = tid >> 6, lane = tid & 63;
  const int n0 = wave * 64;
  const int lr = lane & 15, lg = lane >> 4;

  f32x4 acc[4][4];
  #pragma unroll
  for (int i = 0; i < 4; ++i)
    #pragma unroll
    for (int j = 0; j < 4; ++j) acc[i][j] = (f32x4){0.f,0.f,0.f,0.f};

  #pragma unroll
  for (int ks = 0; ks < 2; ++ks) {
    f16x8 af[4], bfr[4];
    #pragma unroll
    for (int mi = 0; mi < 4; ++mi) {
      int m = mi*16 + lr;
      int hm = ((m & 7) ^ ((m >> 3) & 7)) << 4;
      af[mi] = *(const f16x8*)(wl + m*128 + ((ks*64 + lg*16) ^ hm));
    }
    #pragma unroll
    for (int ni = 0; ni < 4; ++ni) {
      int p = n0 + ni*16 + lr;
      int hp = ((p & 7) ^ ((p >> 3) & 7)) << 4;
      bfr[ni] = *(const f16x8*)(xs + p*128 + ((ks*64 + lg*16) ^ hp));
    }
    #pragma unroll
    for (int mi = 0; mi < 4; ++mi)
      #pragma unroll
      for (int ni = 0; ni < 4; ++ni)
        acc[mi][ni] = __builtin_amdgcn_mfma_f32_16x16x32_f16(
            af[mi], bfr[ni], acc[mi][ni], 0, 0, 0);
  }

  const long long obase = (long long)b*64*HW + (long long)y*256;
  #pragma unroll
  for (int mi = 0; mi < 4; ++mi)
    #pragma unroll
    for (int ni = 0; ni < 4; ++ni)
      #pragma unroll
      for (int r = 0; r < 4; ++r) {
        int m = mi*16 + lg*4 + r;
        int p = n0 + ni*16 + lr;
        out[obase + (long long)m*HW + p] = acc[mi][ni][r];
      }
}

// ---------------------------------------------------------------------------
extern "C" void kernel_launch(void* const* d_in, const int* in_sizes, int n_in,
                              void* d_out, int out_size, void* d_ws, size_t ws_size,
                              hipStream_t stream)
{
  float* out = (float*)d_out;

  int mp[7] = {-1,-1,-1,-1,-1,-1,-1};
  bool ok = (n_in == 7);
  if (ok) {
    int n4 = 0;
    for (int i = 0; i < 7; ++i) {
      long s = in_sizes[i];
      if      (s == 33554432) mp[0] = i;            // x
      else if (s == 576)      mp[2] = i;            // w_gate_dw
      else if (s == 12288)    mp[3] = i;            // w_qkv
      else if (s == 1728)     mp[4] = i;            // w_qkv_dw
      else if (s == 8)        mp[6] = i;            // temperature
      else if (s == 4096)     { if (n4 == 0) mp[1] = i; else mp[5] = i; ++n4; }
    }
    ok = ok && (n4 == 2);
    for (int i = 0; i < 7; ++i) ok = ok && (mp[i] >= 0);
  }
  if (!ok) { k_signal<<<2048,256,0,stream>>>(out, (long long)out_size, 2000.0f); return; }
  if (out_size != 33554432) { k_signal<<<2048,256,0,stream>>>(out, (long long)out_size, 3000.0f); return; }

  const float* x    = (const float*)d_in[mp[0]];
  const float* wg   = (const float*)d_in[mp[1]];
  const float* wgd  = (const float*)d_in[mp[2]];
  const float* wqkv = (const float*)d_in[mp[3]];
  const float* wqd  = (const float*)d_in[mp[4]];
  const float* wpj  = (const float*)d_in[mp[5]];
  const float* tp   = (const float*)d_in[mp[6]];

  unsigned char* ws = (unsigned char*)d_ws;
  const size_t GRP_SZ   = 8UL*8*NBAND*80*4;            // 327,680
  const size_t FULL     = 402653184UL + GRP_SZ + 16384UL + 32768UL;
  const size_t PERB_GRP = 8UL*NBAND*80*4;              // 40,960
  const size_t PERB     = 50331648UL + PERB_GRP + 2048UL + 32768UL;

  if (ws != nullptr && ws_size >= FULL) {
    f16*   A    = (f16*)ws;
    f16*   Vv   = (f16*)(ws + 268435456UL);
    f16*   GG   = (f16*)(ws + 335544320UL);
    float* GRP  = (float*)(ws + 402653184UL);
    float* ATT  = (float*)(ws + 402653184UL + GRP_SZ);
    f16*   W16  = (f16*)(ws + 402653184UL + GRP_SZ + 16384UL);
    k0_wconv<<<16,   256, 0, stream>>>(wg, wqkv, W16);
    k1_mfma <<<2048, 256, 0, stream>>>(x, W16, A);
    k2a_dw  <<<4096, 256, 0, stream>>>(A, wgd, wqd, Vv, GG);
    k2b_qk  <<<8*8*NBAND, 64, 0, stream>>>(A, wqd, GRP);
    k2c_attn<<<64,   64,  0, stream>>>(GRP, tp, ATT);
    k3_out  <<<2048, 256, 0, stream>>>(Vv, GG, ATT, wpj, out);
  } else if (ws != nullptr && ws_size >= PERB) {
    f16*   A    = (f16*)ws;
    f16*   Vv   = (f16*)(ws + 33554432UL);
    f16*   GG   = (f16*)(ws + 41943040UL);
    float* GRP  = (float*)(ws + 50331648UL);
    float* ATT  = (float*)(ws + 50331648UL + PERB_GRP);
    f16*   W16  = (f16*)(ws + 50331648UL + PERB_GRP + 2048UL);
    k0_wconv<<<16, 256, 0, stream>>>(wg, wqkv, W16);
    for (int b = 0; b < 8; ++b) {
      const float* xb = x + (long long)b*64*HW;
      float* ob = out + (long long)b*64*HW;
      k1_mfma <<<256,  256, 0, stream>>>(xb, W16, A);
      k2a_dw  <<<512,  256, 0, stream>>>(A, wgd, wqd, Vv, GG);
      k2b_qk  <<<8*NBAND, 64, 0, stream>>>(A, wqd, GRP);
      k2c_attn<<<8,    64,  0, stream>>>(GRP, tp, ATT);
      k3_out  <<<256,  256, 0, stream>>>(Vv, GG, ATT, wpj, ob);
    }
  } else {
    k_signal<<<2048,256,0,stream>>>(out, (long long)out_size, 1000.0f);
  }
}